// Round 18
// baseline (260.432 us; speedup 1.0000x reference)
//
#include <hip/hip_runtime.h>
#include <hip/hip_fp16.h>

#define NN     10000
#define DI     128
#define DO     256
#define KNB    32
#define NSRC   33      // 32 neighbors + self
#define RB     16
#define NP2    10240
#define NTILE  640     // NP2/16 tiles (B side; A reuses these fragments)
#define ATILE  626     // row tiles (covers 10016 rows, pad zeroed)
#define NROWS  10016
#define NCB    20      // col blocks of 512
#define SEG    64      // per-(row,colblock) LDS staging capacity
#define CAP    1024    // per-row compact capacity (count ~312 +- 77 -> 9 sigma)
#define RCAND  128     // candidates entering f64 re-rank (64th key16 + ties)
#define NEG    0.2f

typedef __attribute__((ext_vector_type(8))) short bf16x8;
typedef __attribute__((ext_vector_type(4))) float f32x4;

// monotone map f32 -> u32 preserving < order (handles negatives)
__device__ __forceinline__ unsigned fkey(float f) {
    unsigned u = __float_as_uint(f);
    return (u & 0x80000000u) ? ~u : (u | 0x80000000u);
}
__device__ __forceinline__ unsigned short bf16rne(float f) {
    unsigned u = __float_as_uint(f);
    unsigned r = u + 0x7FFFu + ((u >> 16) & 1u);
    return (unsigned short)(r >> 16);
}

// Fused prep: stage 16 rows of x, emit bf16(hi) MFMA fragments (shared A/B
// lane layout), f64/f32 norms, zero cnt, AND compute hl16/hr (the former
// hgemm_k) for tiles < NN/16 — x row reads are wave-uniform (s_load).
__global__ __launch_bounds__(256) void prep_k(const float* __restrict__ x,
    unsigned short* __restrict__ Bh, double* __restrict__ sq64,
    float* __restrict__ sq32, unsigned* __restrict__ cnt,
    const float* __restrict__ Wl, const float* __restrict__ bl,
    const float* __restrict__ Wr, const float* __restrict__ br,
    __half* __restrict__ hl16, float* __restrict__ hr)
{
    __shared__ float xs[16][132];   // +4 pad: conflict-free strided reads
    const int t = threadIdx.x;
    const int tile = blockIdx.x;
    const int i0 = tile * 16;
    if (tile < 40) {
        const int idx = tile * 256 + t;
        if (idx < NROWS) cnt[idx] = 0;
    }
#pragma unroll
    for (int q = 0; q < 2; ++q) {
        const int idx = t + 256 * q;
        const int r = idx >> 5, c4 = idx & 31;
        float4 v = make_float4(0.f, 0.f, 0.f, 0.f);
        if (i0 + r < NN) v = *(const float4*)(x + (size_t)(i0 + r) * DI + c4 * 4);
        *(float4*)&xs[r][c4 * 4] = v;
    }
    __syncthreads();
    {
        const int ks = t >> 6, flane = t & 63;
        const int srow = flane & 15;
        const int kb = ks * 32 + ((flane >> 4) & 3) * 8;
        unsigned hi2[4];
#pragma unroll
        for (int j = 0; j < 4; ++j) {
            const float v0 = xs[srow][kb + 2 * j], v1 = xs[srow][kb + 2 * j + 1];
            hi2[j] = (unsigned)bf16rne(v0) | ((unsigned)bf16rne(v1) << 16);
        }
        *(uint4*)(Bh + ((size_t)(tile * 4 + ks) * 64 + flane) * 8) =
            make_uint4(hi2[0], hi2[1], hi2[2], hi2[3]);
    }
    {
        const int row = t >> 4, sub = t & 15;
        double s = 0.0;
#pragma unroll
        for (int q = 0; q < 8; ++q) {
            const float v = xs[row][sub * 8 + q];
            s = fma((double)v, (double)v, s);
        }
#pragma unroll
        for (int off = 8; off >= 1; off >>= 1) s += __shfl_xor(s, off);
        if (sub == 0) {
            const int gi = i0 + row;
            sq32[gi] = (gi < NN) ? (float)s : 0.f;
            if (gi < NROWS) sq64[gi] = s;
        }
    }
    // fused hgemm: h_l = x@W_l + b_l (fp16), h_r = x@W_r + b_r (f32)
    if (tile < NN / RB) {
        const int c = t;
        float accl[RB], accr[RB];
        const float blv = bl[c], brv = br[c];
#pragma unroll
        for (int r = 0; r < RB; ++r) { accl[r] = blv; accr[r] = brv; }
        for (int d = 0; d < DI; ++d) {
            const float wl = Wl[d * DO + c];
            const float wr = Wr[d * DO + c];
#pragma unroll
            for (int r = 0; r < RB; ++r) {
                const float xv = x[(size_t)(i0 + r) * DI + d];  // wave-uniform
                accl[r] = fmaf(xv, wl, accl[r]);
                accr[r] = fmaf(xv, wr, accr[r]);
            }
        }
#pragma unroll
        for (int r = 0; r < RB; ++r) {
            hl16[(size_t)(i0 + r) * DO + c] = __float2half(accl[r]);
            hr[(size_t)(i0 + r) * DO + c] = accr[r];
        }
    }
}

// Per-row threshold from the chunk-0 sample: 16th-smallest u16 key of the
// row's 512 distances -> Trow raw-u32 bound (bitwise-consistent with emit).
__global__ __launch_bounds__(256) void thresh_k(
    const unsigned short* __restrict__ Bh, const float* __restrict__ sq32,
    unsigned* __restrict__ Trow)
{
    __shared__ unsigned short dist16[RB][512];
    const int rt = blockIdx.x;
    const int r0 = rt * 16;
    const int t = threadIdx.x;
    const int wid = t >> 6, lane = t & 63;
    const int wbase = wid * 128, l15 = lane & 15, rgrp = (lane >> 4) * 4;

    bf16x8 ah[4];
#pragma unroll
    for (int ks = 0; ks < 4; ++ks)
        ah[ks] = *(const bf16x8*)(Bh + ((size_t)(rt * 4 + ks) * 64 + lane) * 8);
    float sqiv[4];
#pragma unroll
    for (int rg = 0; rg < 4; ++rg) sqiv[rg] = sq32[r0 + rgrp + rg];

#pragma unroll 1
    for (int ct = 0; ct < 8; ++ct) {
        const int ctg = wid * 8 + ct;
        bf16x8 bh[4];
#pragma unroll
        for (int ks = 0; ks < 4; ++ks)
            bh[ks] = *(const bf16x8*)(Bh + ((size_t)(ctg * 4 + ks) * 64 + lane) * 8);
        f32x4 acc = {0.f, 0.f, 0.f, 0.f};
#pragma unroll
        for (int ks = 0; ks < 4; ++ks)
            acc = __builtin_amdgcn_mfma_f32_16x16x32_bf16(ah[ks], bh[ks], acc, 0, 0, 0);
        const int col = wbase + ct * 16 + l15;
        const float sqj = sq32[col];
#pragma unroll
        for (int rg = 0; rg < 4; ++rg) {
            const int row = r0 + rgrp + rg;
            const float dd = __builtin_fmaf(-2.f, acc[rg], sqiv[rg] + sqj);
            unsigned k16 = (__float_as_uint(dd) >> 16) | 0x8000u;
            if (col >= NN || col == row) k16 = 0xFFFFu;
            dist16[rgrp + rg][col] = (unsigned short)k16;
        }
    }
    __syncthreads();

#pragma unroll 1
    for (int rr = 0; rr < 4; ++rr) {
        const int r = wid * 4 + rr;
        unsigned kk[8];
#pragma unroll
        for (int u = 0; u < 8; ++u) kk[u] = dist16[r][lane + 64 * u];
        unsigned lo = 0, hi = 0xFFFFu;
#pragma unroll 1
        for (int it = 0; it < 16; ++it) {
            const unsigned mid = (lo + hi) >> 1;
            int c2 = 0;
#pragma unroll
            for (int u = 0; u < 8; ++u)
                c2 += (int)__popcll(__ballot(kk[u] <= mid));
            if (c2 >= 16) hi = mid; else lo = mid;
        }
        if (lane == 0) Trow[r0 + r] = ((hi & 0x7FFFu) << 16) | 0xFFFFu;
    }
}

// Main pass: 32 rows x 512 cols per block, hi-only MFMA, threshold compare,
// LDS-atomic append, compact copy. Fast path (18/20 col-blocks) drops the
// col checks. B fragments: 3-buffer, 2-deep prefetch — LOADB(ct+2) issues
// before BODY(ct), covering ~240cy of work per L2 load round-trip.
__global__ __launch_bounds__(256) void knn_emit_k(
    const unsigned short* __restrict__ Bh, const float* __restrict__ sq32,
    const unsigned* __restrict__ Trow, unsigned* __restrict__ cnt,
    unsigned* __restrict__ cand)
{
    __shared__ unsigned lcnt[32];
    __shared__ unsigned basebuf[32];
    __shared__ unsigned cbuf[32][SEG];   // 8 KB
    const int r0 = blockIdx.x * 32;
    const int cbase = blockIdx.y * 512;
    const int t = threadIdx.x;
    const int wid = t >> 6, lane = t & 63;
    const int wbase = wid * 128, l15 = lane & 15, rgrp = (lane >> 4) * 4;
    if (t < 32) lcnt[t] = 0;

    bf16x8 ah[2][4];
#pragma unroll
    for (int rt2 = 0; rt2 < 2; ++rt2)
#pragma unroll
        for (int ks = 0; ks < 4; ++ks) {
            const int rt = (r0 >> 4) + rt2;
            ah[rt2][ks] = *(const bf16x8*)(Bh + ((size_t)(rt * 4 + ks) * 64 + lane) * 8);
        }
    float sqiv[2][4];
    unsigned TUv[2][4];
#pragma unroll
    for (int rt2 = 0; rt2 < 2; ++rt2)
#pragma unroll
        for (int rg = 0; rg < 4; ++rg) {
            const int row = r0 + rt2 * 16 + rgrp + rg;
            sqiv[rt2][rg] = sq32[row];
            TUv[rt2][rg] = Trow[row];
        }
    float sqjv[8];
    unsigned colOr[8];
#pragma unroll
    for (int ct = 0; ct < 8; ++ct) {
        const int col = cbase + wbase + ct * 16 + l15;
        sqjv[ct] = sq32[col];
        colOr[ct] = 0x80000000u | (unsigned)col;
    }
    __syncthreads();

    const int ctg0 = (cbase >> 4) + wid * 8;
    const bool safe = ((blockIdx.x >> 4) != blockIdx.y) && (blockIdx.y != NCB - 1);

#define LOADB(DST, CT) { \
    _Pragma("unroll") \
    for (int ks = 0; ks < 4; ++ks) \
        DST[ks] = *(const bf16x8*)(Bh + ((size_t)((ctg0 + (CT)) * 4 + ks) * 64 + lane) * 8); }

#define BODY(BHREG, CT, CHK) { \
    f32x4 a0 = {0.f,0.f,0.f,0.f}, a1 = {0.f,0.f,0.f,0.f}; \
    _Pragma("unroll") \
    for (int ks = 0; ks < 4; ++ks) { \
        a0 = __builtin_amdgcn_mfma_f32_16x16x32_bf16(ah[0][ks], BHREG[ks], a0, 0, 0, 0); \
        a1 = __builtin_amdgcn_mfma_f32_16x16x32_bf16(ah[1][ks], BHREG[ks], a1, 0, 0, 0); } \
    const float sqj = sqjv[CT]; \
    const unsigned co = colOr[CT]; \
    _Pragma("unroll") \
    for (int rt2 = 0; rt2 < 2; ++rt2) \
    _Pragma("unroll") \
    for (int rg = 0; rg < 4; ++rg) { \
        const int lrow = rt2 * 16 + rgrp + rg; \
        const float dd = __builtin_fmaf(-2.f, (rt2 ? a1 : a0)[rg], sqiv[rt2][rg] + sqj); \
        const unsigned raw = __float_as_uint(dd); \
        bool pass = raw <= TUv[rt2][rg]; \
        if (CHK) { \
            const int col = (int)(co & 0xFFFFu); \
            pass = pass && (col < NN) && (col != r0 + lrow); \
        } \
        if (pass) { \
            const unsigned slot = atomicAdd(&lcnt[lrow], 1u); \
            if (slot < SEG) cbuf[lrow][slot] = (raw & 0xFFFF0000u) | co; \
        } } }

    bf16x8 bA[4], bB[4], bC[4];
    LOADB(bA, 0)
    LOADB(bB, 1)
    if (safe) {
        LOADB(bC, 2) BODY(bA, 0, false)
        LOADB(bA, 3) BODY(bB, 1, false)
        LOADB(bB, 4) BODY(bC, 2, false)
        LOADB(bC, 5) BODY(bA, 3, false)
        LOADB(bA, 6) BODY(bB, 4, false)
        LOADB(bB, 7) BODY(bC, 5, false)
        BODY(bA, 6, false)
        BODY(bB, 7, false)
    } else {
        LOADB(bC, 2) BODY(bA, 0, true)
        LOADB(bA, 3) BODY(bB, 1, true)
        LOADB(bB, 4) BODY(bC, 2, true)
        LOADB(bC, 5) BODY(bA, 3, true)
        LOADB(bA, 6) BODY(bB, 4, true)
        LOADB(bB, 7) BODY(bC, 5, true)
        BODY(bA, 6, true)
        BODY(bB, 7, true)
    }
#undef BODY
#undef LOADB

    __syncthreads();
    if (t < 32) {
        unsigned c = lcnt[t]; if (c > SEG) c = SEG;
        lcnt[t] = c;
        basebuf[t] = atomicAdd(&cnt[r0 + t], c);   // one atomic per row per block
    }
    __syncthreads();
#pragma unroll
    for (int q = 0; q < (32 * SEG) / 256; ++q) {
        const int idx = t + 256 * q;
        const int lr = idx >> 6, sl = idx & 63;
        if ((unsigned)sl < lcnt[lr]) {
            const unsigned b = basebuf[lr] + (unsigned)sl;
            if (b < CAP) cand[(size_t)(r0 + lr) * CAP + b] = cbuf[lr][sl];
        }
    }
}

// One row per block (256 threads). 2-level radix histogram finds the exact
// 64th-smallest key16 (T16); emit all key16 <= T16 (cap 128, superset of
// top-64); f64 re-rank with 2 lanes/cand (32B-interleaved coalesced loads);
// LDS-broadcast rank loop scatters the final top-32 by (f32-dist, col).
__global__ __launch_bounds__(256) void rerank_select_k(
    const float* __restrict__ x, const double* __restrict__ sq64,
    const unsigned* __restrict__ cand, const unsigned* __restrict__ cnt,
    int* __restrict__ nbr)
{
    __shared__ unsigned hist[256];
    __shared__ unsigned hist2[256];
    __shared__ float xrs[DI];
    __shared__ unsigned cbuf[RCAND];
    __shared__ unsigned long long kbuf[RCAND];
    __shared__ unsigned sel[4];   // [0]=H, [1]=r, [2]=T16, [3]=emit base
    const int i = blockIdx.x, t = threadIdx.x;
    const int lane = t & 63;

    hist[t] = 0; hist2[t] = 0;
    if (t < RCAND) cbuf[t] = 0xFFFFFFFFu;
    if (t >= 128 && t < 160)
        *(float4*)&xrs[(t - 128) * 4] =
            *(const float4*)(x + (size_t)i * DI + (t - 128) * 4);
    if (t == 0) { sel[0] = 0xFFFFFFFFu; sel[2] = 0xFFFFu; sel[3] = 0; }
    unsigned n = cnt[i]; if (n > CAP) n = CAP;
    unsigned kk[4];
#pragma unroll
    for (int u = 0; u < 4; ++u) {
        const unsigned idx = (unsigned)t + 256u * u;
        kk[u] = (idx < n) ? cand[(size_t)i * CAP + idx] : 0xFFFFFFFFu;
    }
    __syncthreads();

    // level 1: histogram of key16 high byte
#pragma unroll
    for (int u = 0; u < 4; ++u)
        if (kk[u] != 0xFFFFFFFFu) atomicAdd(&hist[kk[u] >> 24], 1u);
    __syncthreads();
    if (t < 64) {   // wave 0: exclusive scan over 256 buckets, locate H and r
        unsigned h[4];
#pragma unroll
        for (int q = 0; q < 4; ++q) h[q] = hist[lane * 4 + q];
        const unsigned s = h[0] + h[1] + h[2] + h[3];
        unsigned pre = s;
#pragma unroll
        for (int off = 1; off < 64; off <<= 1) {
            const unsigned o = __shfl_up(pre, off);
            if (lane >= off) pre += o;
        }
        const unsigned B = pre - s;
        if (B < 64 && B + s >= 64) {   // this lane's 4 buckets contain rank 64
            unsigned c = B, H = 0, rr = 0;
#pragma unroll
            for (int q = 0; q < 4; ++q) {
                if (c < 64 && c + h[q] >= 64) { H = lane * 4 + q; rr = 64 - c; break; }
                c += h[q];
            }
            sel[0] = H; sel[1] = rr;
        }
    }
    __syncthreads();
    const unsigned H = sel[0];

    // level 2: histogram of low byte within bucket H
    if (H != 0xFFFFFFFFu) {
#pragma unroll
        for (int u = 0; u < 4; ++u)
            if (kk[u] != 0xFFFFFFFFu && (kk[u] >> 24) == H)
                atomicAdd(&hist2[(kk[u] >> 16) & 0xFFu], 1u);
    }
    __syncthreads();
    if (t < 64 && H != 0xFFFFFFFFu) {
        const unsigned r = sel[1];
        unsigned h[4];
#pragma unroll
        for (int q = 0; q < 4; ++q) h[q] = hist2[lane * 4 + q];
        const unsigned s = h[0] + h[1] + h[2] + h[3];
        unsigned pre = s;
#pragma unroll
        for (int off = 1; off < 64; off <<= 1) {
            const unsigned o = __shfl_up(pre, off);
            if (lane >= off) pre += o;
        }
        const unsigned B = pre - s;
        if (B < r && B + s >= r) {
            unsigned c = B, L = 0;
#pragma unroll
            for (int q = 0; q < 4; ++q) {
                if (c < r && c + h[q] >= r) { L = lane * 4 + q; break; }
                c += h[q];
            }
            sel[2] = (H << 8) | L;
        }
    }
    __syncthreads();
    const unsigned T16 = sel[2];

    // emit all candidates with key16 <= T16 (cap RCAND)
    {
        const unsigned long long lml = (1ull << lane) - 1;
#pragma unroll
        for (int u = 0; u < 4; ++u) {
            const bool pass = (kk[u] != 0xFFFFFFFFu) && ((kk[u] >> 16) <= T16);
            const unsigned long long b = __ballot(pass);
            unsigned base = 0;
            if (lane == 0 && b) base = atomicAdd(&sel[3], (unsigned)__popcll(b));
            base = __shfl(base, 0);
            if (pass) {
                const int slot = (int)(base + (unsigned)__popcll(b & lml));
                if (slot < RCAND) cbuf[slot] = kk[u];
            }
        }
    }
    __syncthreads();

    // f64 dot: 2 lanes per candidate, pair reads contiguous 32B per step
    const int c = t >> 1, h = t & 1;
    const unsigned cc = cbuf[c];
    const int col = (int)(cc & 0xFFFFu);
    const bool valid = col < NN;
    const float* xc = x + (size_t)(valid ? col : 0) * DI;
    double a = 0.0;
#pragma unroll
    for (int q = 0; q < 16; ++q) {
        const int fi = q * 8 + h * 4;
        const float4 v = *(const float4*)(xc + fi);
        const float4 r4 = *(const float4*)(&xrs[fi]);
        a = fma((double)r4.x, (double)v.x, a);
        a = fma((double)r4.y, (double)v.y, a);
        a = fma((double)r4.z, (double)v.z, a);
        a = fma((double)r4.w, (double)v.w, a);
    }
    a += __shfl_xor(a, 1);
    if (h == 0) {
        unsigned long long key = ~0ull;
        if (valid) {
            const float dd = (float)(sq64[i] + sq64[col] - 2.0 * a);
            key = ((unsigned long long)fkey(dd) << 32) | (unsigned)col;
        }
        kbuf[c] = key;
    }
    __syncthreads();

    // rank by (f32 dist, col); scatter top-32 (slot = rank)
    if (t < RCAND) {
        const unsigned long long key = kbuf[t];
        int rank = 0;
#pragma unroll 8
        for (int j = 0; j < RCAND; ++j)
            rank += (kbuf[j] < key) ? 1 : 0;
        if (key != ~0ull && rank < KNB)
            nbr[(size_t)i * KNB + rank] = (int)(key & 0xFFFFu);
    }
}

// attention epilogue: block=row. Stage all 33 hl16 rows in LDS once;
// e-phase: wave w owns k in {w, w+4, ...} (4 dims/lane, intra-wave reduce);
// softmax on wave 0; output phase reads LDS (2-way bank alias = free).
__global__ __launch_bounds__(256) void gat_k(
    const __half* __restrict__ hl16, const float* __restrict__ hr,
    const int* __restrict__ nbr, const float* __restrict__ att,
    const float* __restrict__ bias, float* __restrict__ out)
{
    __shared__ int src[NSRC];
    __shared__ __align__(16) __half hbuf[NSRC][DO];   // 16,896 B
    __shared__ float eS[NSRC];
    __shared__ float alphaS[NSRC];
    const int i = blockIdx.x, t = threadIdx.x;
    if (t < KNB) src[t] = nbr[(size_t)i * KNB + t];
    if (t == KNB) src[KNB] = i;   // self-loop appended last
    __syncthreads();

    {   // stage 33 rows: 32 threads x 16B per row
        const int sub = t & 31, rb = t >> 5;
#pragma unroll
        for (int s = 0; s < 5; ++s) {
            const int rk = s * 8 + rb;
            if (rk < NSRC)
                *(uint4*)&hbuf[rk][sub * 8] =
                    *(const uint4*)(hl16 + (size_t)src[rk] * DO + sub * 8);
        }
    }
    __syncthreads();

    const int wid = t >> 6, lane = t & 63;
    {
        const float4 hr4 = *(const float4*)(hr + (size_t)i * DO + lane * 4);
        const float4 at4 = *(const float4*)(att + lane * 4);
#pragma unroll 1
        for (int k = wid; k < NSRC; k += 4) {
            const __half2 h01 = *(const __half2*)&hbuf[k][lane * 4];
            const __half2 h23 = *(const __half2*)&hbuf[k][lane * 4 + 2];
            const float2 f01 = __half22float2(h01);
            const float2 f23 = __half22float2(h23);
            float z, p = 0.f;
            z = f01.x + hr4.x; p = fmaf(z > 0.f ? z : NEG * z, at4.x, p);
            z = f01.y + hr4.y; p = fmaf(z > 0.f ? z : NEG * z, at4.y, p);
            z = f23.x + hr4.z; p = fmaf(z > 0.f ? z : NEG * z, at4.z, p);
            z = f23.y + hr4.w; p = fmaf(z > 0.f ? z : NEG * z, at4.w, p);
#pragma unroll
            for (int off = 32; off >= 1; off >>= 1) p += __shfl_xor(p, off);
            if (lane == 0) eS[k] = p;
        }
    }
    __syncthreads();
    if (wid == 0) {
        const float v = (lane < NSRC) ? eS[lane] : -3.4e38f;
        float m = v;
#pragma unroll
        for (int off = 32; off >= 1; off >>= 1) m = fmaxf(m, __shfl_xor(m, off));
        float w = (lane < NSRC) ? __expf(v - m) : 0.f;
        float s = w;
#pragma unroll
        for (int off = 32; off >= 1; off >>= 1) s += __shfl_xor(s, off);
        if (lane < NSRC) alphaS[lane] = w / s;
    }
    __syncthreads();
    float o = bias[t];
#pragma unroll
    for (int k = 0; k < NSRC; ++k)
        o = fmaf(alphaS[k], __half2float(hbuf[k][t]), o);
    out[(size_t)i * DO + t] = o;
}

extern "C" void kernel_launch(void* const* d_in, const int* in_sizes, int n_in,
                              void* d_out, int out_size, void* d_ws, size_t ws_size,
                              hipStream_t stream) {
    const float* x    = (const float*)d_in[0];
    const float* Wl   = (const float*)d_in[1];
    const float* bl   = (const float*)d_in[2];
    const float* Wr   = (const float*)d_in[3];
    const float* br   = (const float*)d_in[4];
    const float* att  = (const float*)d_in[5];
    const float* bias = (const float*)d_in[6];
    float* out = (float*)d_out;

    char* ws = (char*)d_ws;
    unsigned short* Bh  = (unsigned short*)(ws + 0);          //  2,621,440
    double* sq64 = (double*)(ws + 2621440);                   //     80,128
    float*  sq32 = (float*)(ws + 2701568);                    //     40,960
    unsigned* Trow = (unsigned*)(ws + 2742528);               //     40,064
    unsigned* cnt  = (unsigned*)(ws + 2782592);               //     40,064
    int*    nbr  = (int*)(ws + 2822656);                      //  1,280,000
    unsigned* cand = (unsigned*)(ws + 4102656);               // 41,025,536
    __half* hl16 = (__half*)(ws + 45128192);                  //  5,120,000
    float*  hr   = (float*)(ws + 50248192);                   // 10,240,000
    // total = 60,488,192 bytes

    prep_k<<<dim3(NTILE), 256, 0, stream>>>(x, Bh, sq64, sq32, cnt,
                                            Wl, bl, Wr, br, hl16, hr);
    thresh_k<<<dim3(ATILE), 256, 0, stream>>>(Bh, sq32, Trow);
    knn_emit_k<<<dim3(ATILE / 2, NCB), 256, 0, stream>>>(Bh, sq32, Trow, cnt, cand);
    rerank_select_k<<<dim3(NN), 256, 0, stream>>>(x, sq64, cand, cnt, nbr);
    gat_k<<<dim3(NN), 256, 0, stream>>>(hl16, hr, nbr, att, bias, out);
}

// Round 19
// 230.420 us; speedup vs baseline: 1.1302x; 1.1302x over previous
//
#include <hip/hip_runtime.h>
#include <hip/hip_fp16.h>

#define NN     10000
#define DI     128
#define DO     256
#define KNB    32
#define NSRC   33      // 32 neighbors + self
#define RB     16
#define NP2    10240
#define NTILE  640     // NP2/16 tiles (B side; A reuses these fragments)
#define ATILE  626     // row tiles (covers 10016 rows, pad zeroed)
#define NROWS  10016
#define NCB    20      // col blocks of 512
#define SEG    64      // per-(row,colblock) LDS staging capacity
#define CAP    1024    // per-row compact capacity (count ~312 +- 77 -> 9 sigma)
#define RCAND  128     // candidates entering f64 re-rank (64th key16 + ties)
#define NEG    0.2f

typedef __attribute__((ext_vector_type(8))) short bf16x8;
typedef __attribute__((ext_vector_type(4))) float f32x4;

// monotone map f32 -> u32 preserving < order (handles negatives)
__device__ __forceinline__ unsigned fkey(float f) {
    unsigned u = __float_as_uint(f);
    return (u & 0x80000000u) ? ~u : (u | 0x80000000u);
}
__device__ __forceinline__ unsigned short bf16rne(float f) {
    unsigned u = __float_as_uint(f);
    unsigned r = u + 0x7FFFu + ((u >> 16) & 1u);
    return (unsigned short)(r >> 16);
}

// Fused prep: stage 16 rows of x, emit bf16(hi) MFMA fragments (shared A/B
// lane layout), f64/f32 norms, zero cnt, AND compute hl16/hr.
__global__ __launch_bounds__(256) void prep_k(const float* __restrict__ x,
    unsigned short* __restrict__ Bh, double* __restrict__ sq64,
    float* __restrict__ sq32, unsigned* __restrict__ cnt,
    const float* __restrict__ Wl, const float* __restrict__ bl,
    const float* __restrict__ Wr, const float* __restrict__ br,
    __half* __restrict__ hl16, float* __restrict__ hr)
{
    __shared__ float xs[16][132];   // +4 pad: conflict-free strided reads
    const int t = threadIdx.x;
    const int tile = blockIdx.x;
    const int i0 = tile * 16;
    if (tile < 40) {
        const int idx = tile * 256 + t;
        if (idx < NROWS) cnt[idx] = 0;
    }
#pragma unroll
    for (int q = 0; q < 2; ++q) {
        const int idx = t + 256 * q;
        const int r = idx >> 5, c4 = idx & 31;
        float4 v = make_float4(0.f, 0.f, 0.f, 0.f);
        if (i0 + r < NN) v = *(const float4*)(x + (size_t)(i0 + r) * DI + c4 * 4);
        *(float4*)&xs[r][c4 * 4] = v;
    }
    __syncthreads();
    {
        const int ks = t >> 6, flane = t & 63;
        const int srow = flane & 15;
        const int kb = ks * 32 + ((flane >> 4) & 3) * 8;
        unsigned hi2[4];
#pragma unroll
        for (int j = 0; j < 4; ++j) {
            const float v0 = xs[srow][kb + 2 * j], v1 = xs[srow][kb + 2 * j + 1];
            hi2[j] = (unsigned)bf16rne(v0) | ((unsigned)bf16rne(v1) << 16);
        }
        *(uint4*)(Bh + ((size_t)(tile * 4 + ks) * 64 + flane) * 8) =
            make_uint4(hi2[0], hi2[1], hi2[2], hi2[3]);
    }
    {
        const int row = t >> 4, sub = t & 15;
        double s = 0.0;
#pragma unroll
        for (int q = 0; q < 8; ++q) {
            const float v = xs[row][sub * 8 + q];
            s = fma((double)v, (double)v, s);
        }
#pragma unroll
        for (int off = 8; off >= 1; off >>= 1) s += __shfl_xor(s, off);
        if (sub == 0) {
            const int gi = i0 + row;
            sq32[gi] = (gi < NN) ? (float)s : 0.f;
            if (gi < NROWS) sq64[gi] = s;
        }
    }
    // fused hgemm: h_l = x@W_l + b_l (fp16), h_r = x@W_r + b_r (f32)
    if (tile < NN / RB) {
        const int c = t;
        float accl[RB], accr[RB];
        const float blv = bl[c], brv = br[c];
#pragma unroll
        for (int r = 0; r < RB; ++r) { accl[r] = blv; accr[r] = brv; }
        for (int d = 0; d < DI; ++d) {
            const float wl = Wl[d * DO + c];
            const float wr = Wr[d * DO + c];
#pragma unroll
            for (int r = 0; r < RB; ++r) {
                const float xv = x[(size_t)(i0 + r) * DI + d];  // wave-uniform
                accl[r] = fmaf(xv, wl, accl[r]);
                accr[r] = fmaf(xv, wr, accr[r]);
            }
        }
#pragma unroll
        for (int r = 0; r < RB; ++r) {
            hl16[(size_t)(i0 + r) * DO + c] = __float2half(accl[r]);
            hr[(size_t)(i0 + r) * DO + c] = accr[r];
        }
    }
}

// Per-row threshold from the chunk-0 sample: 16th-smallest u16 key of the
// row's 512 distances -> Trow raw-u32 bound (bitwise-consistent with emit).
__global__ __launch_bounds__(256) void thresh_k(
    const unsigned short* __restrict__ Bh, const float* __restrict__ sq32,
    unsigned* __restrict__ Trow)
{
    __shared__ unsigned short dist16[RB][512];
    const int rt = blockIdx.x;
    const int r0 = rt * 16;
    const int t = threadIdx.x;
    const int wid = t >> 6, lane = t & 63;
    const int wbase = wid * 128, l15 = lane & 15, rgrp = (lane >> 4) * 4;

    bf16x8 ah[4];
#pragma unroll
    for (int ks = 0; ks < 4; ++ks)
        ah[ks] = *(const bf16x8*)(Bh + ((size_t)(rt * 4 + ks) * 64 + lane) * 8);
    float sqiv[4];
#pragma unroll
    for (int rg = 0; rg < 4; ++rg) sqiv[rg] = sq32[r0 + rgrp + rg];

#pragma unroll 1
    for (int ct = 0; ct < 8; ++ct) {
        const int ctg = wid * 8 + ct;
        bf16x8 bh[4];
#pragma unroll
        for (int ks = 0; ks < 4; ++ks)
            bh[ks] = *(const bf16x8*)(Bh + ((size_t)(ctg * 4 + ks) * 64 + lane) * 8);
        f32x4 acc = {0.f, 0.f, 0.f, 0.f};
#pragma unroll
        for (int ks = 0; ks < 4; ++ks)
            acc = __builtin_amdgcn_mfma_f32_16x16x32_bf16(ah[ks], bh[ks], acc, 0, 0, 0);
        const int col = wbase + ct * 16 + l15;
        const float sqj = sq32[col];
#pragma unroll
        for (int rg = 0; rg < 4; ++rg) {
            const int row = r0 + rgrp + rg;
            const float dd = __builtin_fmaf(-2.f, acc[rg], sqiv[rg] + sqj);
            unsigned k16 = (__float_as_uint(dd) >> 16) | 0x8000u;
            if (col >= NN || col == row) k16 = 0xFFFFu;
            dist16[rgrp + rg][col] = (unsigned short)k16;
        }
    }
    __syncthreads();

#pragma unroll 1
    for (int rr = 0; rr < 4; ++rr) {
        const int r = wid * 4 + rr;
        unsigned kk[8];
#pragma unroll
        for (int u = 0; u < 8; ++u) kk[u] = dist16[r][lane + 64 * u];
        unsigned lo = 0, hi = 0xFFFFu;
#pragma unroll 1
        for (int it = 0; it < 16; ++it) {
            const unsigned mid = (lo + hi) >> 1;
            int c2 = 0;
#pragma unroll
            for (int u = 0; u < 8; ++u)
                c2 += (int)__popcll(__ballot(kk[u] <= mid));
            if (c2 >= 16) hi = mid; else lo = mid;
        }
        if (lane == 0) Trow[r0 + r] = ((hi & 0x7FFFu) << 16) | 0xFFFFu;
    }
}

// Main pass (round-15 body — best measured: 60 VGPR, ~46% occ, 83 us):
// 32 rows x 512 cols per block, hi-only MFMA, threshold compare, per-lane
// LDS-atomic append, compact copy with one global atomic per row per block.
__global__ __launch_bounds__(256) void knn_emit_k(
    const unsigned short* __restrict__ Bh, const float* __restrict__ sq32,
    const unsigned* __restrict__ Trow, unsigned* __restrict__ cnt,
    unsigned* __restrict__ cand)
{
    __shared__ unsigned lcnt[32];
    __shared__ unsigned basebuf[32];
    __shared__ unsigned cbuf[32][SEG];   // 8 KB
    const int r0 = blockIdx.x * 32;
    const int cbase = blockIdx.y * 512;
    const int t = threadIdx.x;
    const int wid = t >> 6, lane = t & 63;
    const int wbase = wid * 128, l15 = lane & 15, rgrp = (lane >> 4) * 4;
    if (t < 32) lcnt[t] = 0;

    bf16x8 ah[2][4];
#pragma unroll
    for (int rt2 = 0; rt2 < 2; ++rt2)
#pragma unroll
        for (int ks = 0; ks < 4; ++ks) {
            const int rt = (r0 >> 4) + rt2;
            ah[rt2][ks] = *(const bf16x8*)(Bh + ((size_t)(rt * 4 + ks) * 64 + lane) * 8);
        }
    float sqiv[2][4];
    unsigned TUv[2][4];
#pragma unroll
    for (int rt2 = 0; rt2 < 2; ++rt2)
#pragma unroll
        for (int rg = 0; rg < 4; ++rg) {
            const int row = r0 + rt2 * 16 + rgrp + rg;
            sqiv[rt2][rg] = sq32[row];
            TUv[rt2][rg] = Trow[row];
        }
    float sqjv[8];
#pragma unroll
    for (int ct = 0; ct < 8; ++ct)
        sqjv[ct] = sq32[cbase + wbase + ct * 16 + l15];
    __syncthreads();

    const int ctg0 = (cbase >> 4) + wid * 8;

#pragma unroll 1
    for (int ct = 0; ct < 8; ++ct) {
        bf16x8 bh[4];
#pragma unroll
        for (int ks = 0; ks < 4; ++ks)
            bh[ks] = *(const bf16x8*)(Bh + ((size_t)((ctg0 + ct) * 4 + ks) * 64 + lane) * 8);
        f32x4 a0 = {0.f, 0.f, 0.f, 0.f}, a1 = {0.f, 0.f, 0.f, 0.f};
#pragma unroll
        for (int ks = 0; ks < 4; ++ks) {
            a0 = __builtin_amdgcn_mfma_f32_16x16x32_bf16(ah[0][ks], bh[ks], a0, 0, 0, 0);
            a1 = __builtin_amdgcn_mfma_f32_16x16x32_bf16(ah[1][ks], bh[ks], a1, 0, 0, 0);
        }
        const int col = cbase + wbase + ct * 16 + l15;
        const float sqj = sqjv[ct];
#pragma unroll
        for (int rt2 = 0; rt2 < 2; ++rt2)
#pragma unroll
            for (int rg = 0; rg < 4; ++rg) {
                const int lrow = rt2 * 16 + rgrp + rg;
                const float dd = __builtin_fmaf(-2.f, (rt2 ? a1 : a0)[rg],
                                                sqiv[rt2][rg] + sqj);
                const unsigned raw = __float_as_uint(dd);
                if ((raw <= TUv[rt2][rg]) && (col < NN) && (col != r0 + lrow)) {
                    const unsigned slot = atomicAdd(&lcnt[lrow], 1u);
                    if (slot < SEG)
                        cbuf[lrow][slot] =
                            (((raw >> 16) | 0x8000u) << 16) | (unsigned)col;
                }
            }
    }

    __syncthreads();
    if (t < 32) {
        unsigned c = lcnt[t]; if (c > SEG) c = SEG;
        lcnt[t] = c;
        basebuf[t] = atomicAdd(&cnt[r0 + t], c);   // one atomic per row per block
    }
    __syncthreads();
#pragma unroll
    for (int q = 0; q < (32 * SEG) / 256; ++q) {
        const int idx = t + 256 * q;
        const int lr = idx >> 6, sl = idx & 63;
        if ((unsigned)sl < lcnt[lr]) {
            const unsigned b = basebuf[lr] + (unsigned)sl;
            if (b < CAP) cand[(size_t)(r0 + lr) * CAP + b] = cbuf[lr][sl];
        }
    }
}

// Fused per-row tail: histogram top-64 select -> f64 re-rank -> rank ->
// GAT attention epilogue, all in one block (no nbr round-trip, no grid-wide
// barrier between neighbor selection and attention).
__global__ __launch_bounds__(256) void rerank_gat_k(
    const float* __restrict__ x, const double* __restrict__ sq64,
    const unsigned* __restrict__ cand, const unsigned* __restrict__ cnt,
    const __half* __restrict__ hl16, const float* __restrict__ hr,
    const float* __restrict__ att, const float* __restrict__ bias,
    float* __restrict__ out)
{
    __shared__ unsigned hist[256];
    __shared__ unsigned hist2[256];
    __shared__ float xrs[DI];
    __shared__ unsigned cbuf[RCAND];
    __shared__ unsigned long long kbuf[RCAND];
    __shared__ unsigned sel[4];   // [0]=H, [1]=r, [2]=T16, [3]=emit base
    __shared__ int srcS[NSRC];
    __shared__ __align__(16) __half hbuf[NSRC][DO];   // 16,896 B
    __shared__ float eS[NSRC];
    __shared__ float alphaS[NSRC];
    const int i = blockIdx.x, t = threadIdx.x;
    const int lane = t & 63;

    hist[t] = 0; hist2[t] = 0;
    if (t < RCAND) cbuf[t] = 0xFFFFFFFFu;
    if (t >= 128 && t < 160)
        *(float4*)&xrs[(t - 128) * 4] =
            *(const float4*)(x + (size_t)i * DI + (t - 128) * 4);
    if (t == 0) { sel[0] = 0xFFFFFFFFu; sel[2] = 0xFFFFu; sel[3] = 0; }
    unsigned n = cnt[i]; if (n > CAP) n = CAP;
    unsigned kk[4];
#pragma unroll
    for (int u = 0; u < 4; ++u) {
        const unsigned idx = (unsigned)t + 256u * u;
        kk[u] = (idx < n) ? cand[(size_t)i * CAP + idx] : 0xFFFFFFFFu;
    }
    __syncthreads();

    // level 1: histogram of key16 high byte
#pragma unroll
    for (int u = 0; u < 4; ++u)
        if (kk[u] != 0xFFFFFFFFu) atomicAdd(&hist[kk[u] >> 24], 1u);
    __syncthreads();
    if (t < 64) {   // wave 0: exclusive scan over 256 buckets, locate H and r
        unsigned h[4];
#pragma unroll
        for (int q = 0; q < 4; ++q) h[q] = hist[lane * 4 + q];
        const unsigned s = h[0] + h[1] + h[2] + h[3];
        unsigned pre = s;
#pragma unroll
        for (int off = 1; off < 64; off <<= 1) {
            const unsigned o = __shfl_up(pre, off);
            if (lane >= off) pre += o;
        }
        const unsigned B = pre - s;
        if (B < 64 && B + s >= 64) {
            unsigned c = B, H = 0, rr = 0;
#pragma unroll
            for (int q = 0; q < 4; ++q) {
                if (c < 64 && c + h[q] >= 64) { H = lane * 4 + q; rr = 64 - c; break; }
                c += h[q];
            }
            sel[0] = H; sel[1] = rr;
        }
    }
    __syncthreads();
    const unsigned H = sel[0];

    // level 2: histogram of low byte within bucket H
    if (H != 0xFFFFFFFFu) {
#pragma unroll
        for (int u = 0; u < 4; ++u)
            if (kk[u] != 0xFFFFFFFFu && (kk[u] >> 24) == H)
                atomicAdd(&hist2[(kk[u] >> 16) & 0xFFu], 1u);
    }
    __syncthreads();
    if (t < 64 && H != 0xFFFFFFFFu) {
        const unsigned r = sel[1];
        unsigned h[4];
#pragma unroll
        for (int q = 0; q < 4; ++q) h[q] = hist2[lane * 4 + q];
        const unsigned s = h[0] + h[1] + h[2] + h[3];
        unsigned pre = s;
#pragma unroll
        for (int off = 1; off < 64; off <<= 1) {
            const unsigned o = __shfl_up(pre, off);
            if (lane >= off) pre += o;
        }
        const unsigned B = pre - s;
        if (B < r && B + s >= r) {
            unsigned c = B, L = 0;
#pragma unroll
            for (int q = 0; q < 4; ++q) {
                if (c < r && c + h[q] >= r) { L = lane * 4 + q; break; }
                c += h[q];
            }
            sel[2] = (H << 8) | L;
        }
    }
    __syncthreads();
    const unsigned T16 = sel[2];

    // emit all candidates with key16 <= T16 (cap RCAND)
    {
        const unsigned long long lml = (1ull << lane) - 1;
#pragma unroll
        for (int u = 0; u < 4; ++u) {
            const bool pass = (kk[u] != 0xFFFFFFFFu) && ((kk[u] >> 16) <= T16);
            const unsigned long long b = __ballot(pass);
            unsigned base = 0;
            if (lane == 0 && b) base = atomicAdd(&sel[3], (unsigned)__popcll(b));
            base = __shfl(base, 0);
            if (pass) {
                const int slot = (int)(base + (unsigned)__popcll(b & lml));
                if (slot < RCAND) cbuf[slot] = kk[u];
            }
        }
    }
    __syncthreads();

    // f64 dot: 2 lanes per candidate, pair reads contiguous 32B per step
    const int c = t >> 1, h = t & 1;
    const unsigned cc = cbuf[c];
    const int col = (int)(cc & 0xFFFFu);
    const bool valid = col < NN;
    const float* xc = x + (size_t)(valid ? col : 0) * DI;
    double a = 0.0;
#pragma unroll
    for (int q = 0; q < 16; ++q) {
        const int fi = q * 8 + h * 4;
        const float4 v = *(const float4*)(xc + fi);
        const float4 r4 = *(const float4*)(&xrs[fi]);
        a = fma((double)r4.x, (double)v.x, a);
        a = fma((double)r4.y, (double)v.y, a);
        a = fma((double)r4.z, (double)v.z, a);
        a = fma((double)r4.w, (double)v.w, a);
    }
    a += __shfl_xor(a, 1);
    if (h == 0) {
        unsigned long long key = ~0ull;
        if (valid) {
            const float dd = (float)(sq64[i] + sq64[col] - 2.0 * a);
            key = ((unsigned long long)fkey(dd) << 32) | (unsigned)col;
        }
        kbuf[c] = key;
    }
    __syncthreads();

    // rank by (f32 dist, col); top-32 become the source list (+ self at 32)
    if (t < RCAND) {
        const unsigned long long key = kbuf[t];
        int rank = 0;
#pragma unroll 8
        for (int j = 0; j < RCAND; ++j)
            rank += (kbuf[j] < key) ? 1 : 0;
        if (key != ~0ull && rank < KNB)
            srcS[rank] = (int)(key & 0xFFFFu);
    }
    if (t == 0) srcS[KNB] = i;
    __syncthreads();

    // ---- GAT attention epilogue (reads srcS) ----
    {   // stage 33 hl16 rows: 32 threads x 16B per row
        const int sub = t & 31, rb = t >> 5;
#pragma unroll
        for (int s = 0; s < 5; ++s) {
            const int rk = s * 8 + rb;
            if (rk < NSRC)
                *(uint4*)&hbuf[rk][sub * 8] =
                    *(const uint4*)(hl16 + (size_t)srcS[rk] * DO + sub * 8);
        }
    }
    __syncthreads();

    const int wid = t >> 6;
    {
        const float4 hr4 = *(const float4*)(hr + (size_t)i * DO + lane * 4);
        const float4 at4 = *(const float4*)(att + lane * 4);
#pragma unroll 1
        for (int k = wid; k < NSRC; k += 4) {
            const __half2 h01 = *(const __half2*)&hbuf[k][lane * 4];
            const __half2 h23 = *(const __half2*)&hbuf[k][lane * 4 + 2];
            const float2 f01 = __half22float2(h01);
            const float2 f23 = __half22float2(h23);
            float z, p = 0.f;
            z = f01.x + hr4.x; p = fmaf(z > 0.f ? z : NEG * z, at4.x, p);
            z = f01.y + hr4.y; p = fmaf(z > 0.f ? z : NEG * z, at4.y, p);
            z = f23.x + hr4.z; p = fmaf(z > 0.f ? z : NEG * z, at4.z, p);
            z = f23.y + hr4.w; p = fmaf(z > 0.f ? z : NEG * z, at4.w, p);
#pragma unroll
            for (int off = 32; off >= 1; off >>= 1) p += __shfl_xor(p, off);
            if (lane == 0) eS[k] = p;
        }
    }
    __syncthreads();
    if (wid == 0) {
        const float v = (lane < NSRC) ? eS[lane] : -3.4e38f;
        float m = v;
#pragma unroll
        for (int off = 32; off >= 1; off >>= 1) m = fmaxf(m, __shfl_xor(m, off));
        float w = (lane < NSRC) ? __expf(v - m) : 0.f;
        float s = w;
#pragma unroll
        for (int off = 32; off >= 1; off >>= 1) s += __shfl_xor(s, off);
        if (lane < NSRC) alphaS[lane] = w / s;
    }
    __syncthreads();
    float o = bias[t];
#pragma unroll
    for (int k = 0; k < NSRC; ++k)
        o = fmaf(alphaS[k], __half2float(hbuf[k][t]), o);
    out[(size_t)i * DO + t] = o;
}

extern "C" void kernel_launch(void* const* d_in, const int* in_sizes, int n_in,
                              void* d_out, int out_size, void* d_ws, size_t ws_size,
                              hipStream_t stream) {
    const float* x    = (const float*)d_in[0];
    const float* Wl   = (const float*)d_in[1];
    const float* bl   = (const float*)d_in[2];
    const float* Wr   = (const float*)d_in[3];
    const float* br   = (const float*)d_in[4];
    const float* att  = (const float*)d_in[5];
    const float* bias = (const float*)d_in[6];
    float* out = (float*)d_out;

    char* ws = (char*)d_ws;
    unsigned short* Bh  = (unsigned short*)(ws + 0);          //  2,621,440
    double* sq64 = (double*)(ws + 2621440);                   //     80,128
    float*  sq32 = (float*)(ws + 2701568);                    //     40,960
    unsigned* Trow = (unsigned*)(ws + 2742528);               //     40,064
    unsigned* cnt  = (unsigned*)(ws + 2782592);               //     40,064
    unsigned* cand = (unsigned*)(ws + 2822656);               // 41,025,536
    __half* hl16 = (__half*)(ws + 43848192);                  //  5,120,000
    float*  hr   = (float*)(ws + 48968192);                   // 10,240,000
    // total = 59,208,192 bytes

    prep_k<<<dim3(NTILE), 256, 0, stream>>>(x, Bh, sq64, sq32, cnt,
                                            Wl, bl, Wr, br, hl16, hr);
    thresh_k<<<dim3(ATILE), 256, 0, stream>>>(Bh, sq32, Trow);
    knn_emit_k<<<dim3(ATILE / 2, NCB), 256, 0, stream>>>(Bh, sq32, Trow, cnt, cand);
    rerank_gat_k<<<dim3(NN), 256, 0, stream>>>(x, sq64, cand, cnt,
                                               hl16, hr, att, bias, out);
}

// Round 20
// 219.162 us; speedup vs baseline: 1.1883x; 1.0514x over previous
//
#include <hip/hip_runtime.h>
#include <hip/hip_fp16.h>

#define NN     10000
#define DI     128
#define DO     256
#define KNB    32
#define NSRC   33      // 32 neighbors + self
#define RB     16
#define NP2    10240
#define NTILE  640     // NP2/16 tiles (B side; A reuses these fragments)
#define ATILE  626     // row tiles (covers 10016 rows, pad zeroed)
#define NROWS  10016
#define NCB    20      // col blocks of 512
#define SEG    64      // per-(row,colblock) LDS staging capacity
#define CAP    1024    // per-row compact capacity (count ~312 +- 77 -> 9 sigma)
#define RCAND  128     // candidates entering f64 re-rank (64th key16 + ties)
#define NEG    0.2f

typedef __attribute__((ext_vector_type(8))) short bf16x8;
typedef __attribute__((ext_vector_type(4))) float f32x4;

// monotone map f32 -> u32 preserving < order (handles negatives)
__device__ __forceinline__ unsigned fkey(float f) {
    unsigned u = __float_as_uint(f);
    return (u & 0x80000000u) ? ~u : (u | 0x80000000u);
}
__device__ __forceinline__ unsigned short bf16rne(float f) {
    unsigned u = __float_as_uint(f);
    unsigned r = u + 0x7FFFu + ((u >> 16) & 1u);
    return (unsigned short)(r >> 16);
}

// Fused prep: stage 16 rows of x, emit bf16(hi) MFMA fragments (shared A/B
// lane layout), f64/f32 norms, zero cnt, AND compute hl16/hr.
__global__ __launch_bounds__(256) void prep_k(const float* __restrict__ x,
    unsigned short* __restrict__ Bh, double* __restrict__ sq64,
    float* __restrict__ sq32, unsigned* __restrict__ cnt,
    const float* __restrict__ Wl, const float* __restrict__ bl,
    const float* __restrict__ Wr, const float* __restrict__ br,
    __half* __restrict__ hl16, float* __restrict__ hr)
{
    __shared__ float xs[16][132];   // +4 pad: conflict-free strided reads
    const int t = threadIdx.x;
    const int tile = blockIdx.x;
    const int i0 = tile * 16;
    if (tile < 40) {
        const int idx = tile * 256 + t;
        if (idx < NROWS) cnt[idx] = 0;
    }
#pragma unroll
    for (int q = 0; q < 2; ++q) {
        const int idx = t + 256 * q;
        const int r = idx >> 5, c4 = idx & 31;
        float4 v = make_float4(0.f, 0.f, 0.f, 0.f);
        if (i0 + r < NN) v = *(const float4*)(x + (size_t)(i0 + r) * DI + c4 * 4);
        *(float4*)&xs[r][c4 * 4] = v;
    }
    __syncthreads();
    {
        const int ks = t >> 6, flane = t & 63;
        const int srow = flane & 15;
        const int kb = ks * 32 + ((flane >> 4) & 3) * 8;
        unsigned hi2[4];
#pragma unroll
        for (int j = 0; j < 4; ++j) {
            const float v0 = xs[srow][kb + 2 * j], v1 = xs[srow][kb + 2 * j + 1];
            hi2[j] = (unsigned)bf16rne(v0) | ((unsigned)bf16rne(v1) << 16);
        }
        *(uint4*)(Bh + ((size_t)(tile * 4 + ks) * 64 + flane) * 8) =
            make_uint4(hi2[0], hi2[1], hi2[2], hi2[3]);
    }
    {
        const int row = t >> 4, sub = t & 15;
        double s = 0.0;
#pragma unroll
        for (int q = 0; q < 8; ++q) {
            const float v = xs[row][sub * 8 + q];
            s = fma((double)v, (double)v, s);
        }
#pragma unroll
        for (int off = 8; off >= 1; off >>= 1) s += __shfl_xor(s, off);
        if (sub == 0) {
            const int gi = i0 + row;
            sq32[gi] = (gi < NN) ? (float)s : 0.f;
            if (gi < NROWS) sq64[gi] = s;
        }
    }
    // fused hgemm: h_l = x@W_l + b_l (fp16), h_r = x@W_r + b_r (f32)
    if (tile < NN / RB) {
        const int c = t;
        float accl[RB], accr[RB];
        const float blv = bl[c], brv = br[c];
#pragma unroll
        for (int r = 0; r < RB; ++r) { accl[r] = blv; accr[r] = brv; }
        for (int d = 0; d < DI; ++d) {
            const float wl = Wl[d * DO + c];
            const float wr = Wr[d * DO + c];
#pragma unroll
            for (int r = 0; r < RB; ++r) {
                const float xv = x[(size_t)(i0 + r) * DI + d];  // wave-uniform
                accl[r] = fmaf(xv, wl, accl[r]);
                accr[r] = fmaf(xv, wr, accr[r]);
            }
        }
#pragma unroll
        for (int r = 0; r < RB; ++r) {
            hl16[(size_t)(i0 + r) * DO + c] = __float2half(accl[r]);
            hr[(size_t)(i0 + r) * DO + c] = accr[r];
        }
    }
}

// Per-row threshold from the chunk-0 sample: 16th-smallest u16 key of the
// row's 512 distances -> Trow raw-u32 bound (bitwise-consistent with emit).
__global__ __launch_bounds__(256) void thresh_k(
    const unsigned short* __restrict__ Bh, const float* __restrict__ sq32,
    unsigned* __restrict__ Trow)
{
    __shared__ unsigned short dist16[RB][512];
    const int rt = blockIdx.x;
    const int r0 = rt * 16;
    const int t = threadIdx.x;
    const int wid = t >> 6, lane = t & 63;
    const int wbase = wid * 128, l15 = lane & 15, rgrp = (lane >> 4) * 4;

    bf16x8 ah[4];
#pragma unroll
    for (int ks = 0; ks < 4; ++ks)
        ah[ks] = *(const bf16x8*)(Bh + ((size_t)(rt * 4 + ks) * 64 + lane) * 8);
    float sqiv[4];
#pragma unroll
    for (int rg = 0; rg < 4; ++rg) sqiv[rg] = sq32[r0 + rgrp + rg];

#pragma unroll 1
    for (int ct = 0; ct < 8; ++ct) {
        const int ctg = wid * 8 + ct;
        bf16x8 bh[4];
#pragma unroll
        for (int ks = 0; ks < 4; ++ks)
            bh[ks] = *(const bf16x8*)(Bh + ((size_t)(ctg * 4 + ks) * 64 + lane) * 8);
        f32x4 acc = {0.f, 0.f, 0.f, 0.f};
#pragma unroll
        for (int ks = 0; ks < 4; ++ks)
            acc = __builtin_amdgcn_mfma_f32_16x16x32_bf16(ah[ks], bh[ks], acc, 0, 0, 0);
        const int col = wbase + ct * 16 + l15;
        const float sqj = sq32[col];
#pragma unroll
        for (int rg = 0; rg < 4; ++rg) {
            const int row = r0 + rgrp + rg;
            const float dd = __builtin_fmaf(-2.f, acc[rg], sqiv[rg] + sqj);
            unsigned k16 = (__float_as_uint(dd) >> 16) | 0x8000u;
            if (col >= NN || col == row) k16 = 0xFFFFu;
            dist16[rgrp + rg][col] = (unsigned short)k16;
        }
    }
    __syncthreads();

#pragma unroll 1
    for (int rr = 0; rr < 4; ++rr) {
        const int r = wid * 4 + rr;
        unsigned kk[8];
#pragma unroll
        for (int u = 0; u < 8; ++u) kk[u] = dist16[r][lane + 64 * u];
        unsigned lo = 0, hi = 0xFFFFu;
#pragma unroll 1
        for (int it = 0; it < 16; ++it) {
            const unsigned mid = (lo + hi) >> 1;
            int c2 = 0;
#pragma unroll
            for (int u = 0; u < 8; ++u)
                c2 += (int)__popcll(__ballot(kk[u] <= mid));
            if (c2 >= 16) hi = mid; else lo = mid;
        }
        if (lane == 0) Trow[r0 + r] = ((hi & 0x7FFFu) << 16) | 0xFFFFu;
    }
}

// Main pass (round-15 body — best measured: 60 VGPR, ~46% occ, 83 us):
// 32 rows x 512 cols per block, hi-only MFMA, threshold compare, per-lane
// LDS-atomic append, compact copy with one global atomic per row per block.
__global__ __launch_bounds__(256) void knn_emit_k(
    const unsigned short* __restrict__ Bh, const float* __restrict__ sq32,
    const unsigned* __restrict__ Trow, unsigned* __restrict__ cnt,
    unsigned* __restrict__ cand)
{
    __shared__ unsigned lcnt[32];
    __shared__ unsigned basebuf[32];
    __shared__ unsigned cbuf[32][SEG];   // 8 KB
    const int r0 = blockIdx.x * 32;
    const int cbase = blockIdx.y * 512;
    const int t = threadIdx.x;
    const int wid = t >> 6, lane = t & 63;
    const int wbase = wid * 128, l15 = lane & 15, rgrp = (lane >> 4) * 4;
    if (t < 32) lcnt[t] = 0;

    bf16x8 ah[2][4];
#pragma unroll
    for (int rt2 = 0; rt2 < 2; ++rt2)
#pragma unroll
        for (int ks = 0; ks < 4; ++ks) {
            const int rt = (r0 >> 4) + rt2;
            ah[rt2][ks] = *(const bf16x8*)(Bh + ((size_t)(rt * 4 + ks) * 64 + lane) * 8);
        }
    float sqiv[2][4];
    unsigned TUv[2][4];
#pragma unroll
    for (int rt2 = 0; rt2 < 2; ++rt2)
#pragma unroll
        for (int rg = 0; rg < 4; ++rg) {
            const int row = r0 + rt2 * 16 + rgrp + rg;
            sqiv[rt2][rg] = sq32[row];
            TUv[rt2][rg] = Trow[row];
        }
    float sqjv[8];
#pragma unroll
    for (int ct = 0; ct < 8; ++ct)
        sqjv[ct] = sq32[cbase + wbase + ct * 16 + l15];
    __syncthreads();

    const int ctg0 = (cbase >> 4) + wid * 8;

#pragma unroll 1
    for (int ct = 0; ct < 8; ++ct) {
        bf16x8 bh[4];
#pragma unroll
        for (int ks = 0; ks < 4; ++ks)
            bh[ks] = *(const bf16x8*)(Bh + ((size_t)((ctg0 + ct) * 4 + ks) * 64 + lane) * 8);
        f32x4 a0 = {0.f, 0.f, 0.f, 0.f}, a1 = {0.f, 0.f, 0.f, 0.f};
#pragma unroll
        for (int ks = 0; ks < 4; ++ks) {
            a0 = __builtin_amdgcn_mfma_f32_16x16x32_bf16(ah[0][ks], bh[ks], a0, 0, 0, 0);
            a1 = __builtin_amdgcn_mfma_f32_16x16x32_bf16(ah[1][ks], bh[ks], a1, 0, 0, 0);
        }
        const int col = cbase + wbase + ct * 16 + l15;
        const float sqj = sqjv[ct];
#pragma unroll
        for (int rt2 = 0; rt2 < 2; ++rt2)
#pragma unroll
            for (int rg = 0; rg < 4; ++rg) {
                const int lrow = rt2 * 16 + rgrp + rg;
                const float dd = __builtin_fmaf(-2.f, (rt2 ? a1 : a0)[rg],
                                                sqiv[rt2][rg] + sqj);
                const unsigned raw = __float_as_uint(dd);
                if ((raw <= TUv[rt2][rg]) && (col < NN) && (col != r0 + lrow)) {
                    const unsigned slot = atomicAdd(&lcnt[lrow], 1u);
                    if (slot < SEG)
                        cbuf[lrow][slot] =
                            (((raw >> 16) | 0x8000u) << 16) | (unsigned)col;
                }
            }
    }

    __syncthreads();
    if (t < 32) {
        unsigned c = lcnt[t]; if (c > SEG) c = SEG;
        lcnt[t] = c;
        basebuf[t] = atomicAdd(&cnt[r0 + t], c);   // one atomic per row per block
    }
    __syncthreads();
#pragma unroll
    for (int q = 0; q < (32 * SEG) / 256; ++q) {
        const int idx = t + 256 * q;
        const int lr = idx >> 6, sl = idx & 63;
        if ((unsigned)sl < lcnt[lr]) {
            const unsigned b = basebuf[lr] + (unsigned)sl;
            if (b < CAP) cand[(size_t)(r0 + lr) * CAP + b] = cbuf[lr][sl];
        }
    }
}

// Fused per-row tail: histogram top-64 select -> f64 re-rank (only the
// emitted candidates; 2 independent accumulators) -> rank -> GAT attention.
// NOTE: attention output is permutation-invariant over the source SET, so
// rank-scatter order only determines membership.
__global__ __launch_bounds__(256) void rerank_gat_k(
    const float* __restrict__ x, const double* __restrict__ sq64,
    const unsigned* __restrict__ cand, const unsigned* __restrict__ cnt,
    const __half* __restrict__ hl16, const float* __restrict__ hr,
    const float* __restrict__ att, const float* __restrict__ bias,
    float* __restrict__ out)
{
    __shared__ unsigned hist[256];
    __shared__ unsigned hist2[256];
    __shared__ float xrs[DI];
    __shared__ unsigned cbuf[RCAND];
    __shared__ unsigned long long kbuf[RCAND];
    __shared__ unsigned sel[4];   // [0]=H, [1]=r, [2]=T16, [3]=emit base
    __shared__ int srcS[NSRC];
    __shared__ __align__(16) __half hbuf[NSRC][DO];   // 16,896 B
    __shared__ float eS[NSRC];
    __shared__ float alphaS[NSRC];
    const int i = blockIdx.x, t = threadIdx.x;
    const int lane = t & 63;

    hist[t] = 0; hist2[t] = 0;
    if (t < RCAND) cbuf[t] = 0xFFFFFFFFu;
    if (t >= 128 && t < 160)
        *(float4*)&xrs[(t - 128) * 4] =
            *(const float4*)(x + (size_t)i * DI + (t - 128) * 4);
    if (t == 0) { sel[0] = 0xFFFFFFFFu; sel[2] = 0xFFFFu; sel[3] = 0; }
    unsigned n = cnt[i]; if (n > CAP) n = CAP;
    unsigned kk[4];
#pragma unroll
    for (int u = 0; u < 4; ++u) {
        const unsigned idx = (unsigned)t + 256u * u;
        kk[u] = (idx < n) ? cand[(size_t)i * CAP + idx] : 0xFFFFFFFFu;
    }
    __syncthreads();

    // level 1: histogram of key16 high byte
#pragma unroll
    for (int u = 0; u < 4; ++u)
        if (kk[u] != 0xFFFFFFFFu) atomicAdd(&hist[kk[u] >> 24], 1u);
    __syncthreads();
    if (t < 64) {   // wave 0: exclusive scan over 256 buckets, locate H and r
        unsigned h[4];
#pragma unroll
        for (int q = 0; q < 4; ++q) h[q] = hist[lane * 4 + q];
        const unsigned s = h[0] + h[1] + h[2] + h[3];
        unsigned pre = s;
#pragma unroll
        for (int off = 1; off < 64; off <<= 1) {
            const unsigned o = __shfl_up(pre, off);
            if (lane >= off) pre += o;
        }
        const unsigned B = pre - s;
        if (B < 64 && B + s >= 64) {
            unsigned c = B, H = 0, rr = 0;
#pragma unroll
            for (int q = 0; q < 4; ++q) {
                if (c < 64 && c + h[q] >= 64) { H = lane * 4 + q; rr = 64 - c; break; }
                c += h[q];
            }
            sel[0] = H; sel[1] = rr;
        }
    }
    __syncthreads();
    const unsigned H = sel[0];

    // level 2: histogram of low byte within bucket H
    if (H != 0xFFFFFFFFu) {
#pragma unroll
        for (int u = 0; u < 4; ++u)
            if (kk[u] != 0xFFFFFFFFu && (kk[u] >> 24) == H)
                atomicAdd(&hist2[(kk[u] >> 16) & 0xFFu], 1u);
    }
    __syncthreads();
    if (t < 64 && H != 0xFFFFFFFFu) {
        const unsigned r = sel[1];
        unsigned h[4];
#pragma unroll
        for (int q = 0; q < 4; ++q) h[q] = hist2[lane * 4 + q];
        const unsigned s = h[0] + h[1] + h[2] + h[3];
        unsigned pre = s;
#pragma unroll
        for (int off = 1; off < 64; off <<= 1) {
            const unsigned o = __shfl_up(pre, off);
            if (lane >= off) pre += o;
        }
        const unsigned B = pre - s;
        if (B < r && B + s >= r) {
            unsigned c = B, L = 0;
#pragma unroll
            for (int q = 0; q < 4; ++q) {
                if (c < r && c + h[q] >= r) { L = lane * 4 + q; break; }
                c += h[q];
            }
            sel[2] = (H << 8) | L;
        }
    }
    __syncthreads();
    const unsigned T16 = sel[2];

    // emit all candidates with key16 <= T16 (cap RCAND)
    {
        const unsigned long long lml = (1ull << lane) - 1;
#pragma unroll
        for (int u = 0; u < 4; ++u) {
            const bool pass = (kk[u] != 0xFFFFFFFFu) && ((kk[u] >> 16) <= T16);
            const unsigned long long b = __ballot(pass);
            unsigned base = 0;
            if (lane == 0 && b) base = atomicAdd(&sel[3], (unsigned)__popcll(b));
            base = __shfl(base, 0);
            if (pass) {
                const int slot = (int)(base + (unsigned)__popcll(b & lml));
                if (slot < RCAND) cbuf[slot] = kk[u];
            }
        }
    }
    __syncthreads();

    // f64 dot: 2 lanes per candidate, ONLY for emitted slots (waves with
    // c >= emitted skip wholesale); 2 independent accumulators for ILP.
    const unsigned emitted = sel[3] < RCAND ? sel[3] : RCAND;
    const int c = t >> 1, h = t & 1;
    unsigned long long key = ~0ull;
    if ((unsigned)c < emitted) {
        const unsigned cc = cbuf[c];
        const int col = (int)(cc & 0xFFFFu);
        if (col < NN) {
            const float* xc = x + (size_t)col * DI;
            double aE = 0.0, aO = 0.0;
#pragma unroll
            for (int q = 0; q < 8; ++q) {
                const int fiE = (2 * q) * 8 + h * 4;
                const int fiO = (2 * q + 1) * 8 + h * 4;
                const float4 vE = *(const float4*)(xc + fiE);
                const float4 rE = *(const float4*)(&xrs[fiE]);
                const float4 vO = *(const float4*)(xc + fiO);
                const float4 rO = *(const float4*)(&xrs[fiO]);
                aE = fma((double)rE.x, (double)vE.x, aE);
                aE = fma((double)rE.y, (double)vE.y, aE);
                aE = fma((double)rE.z, (double)vE.z, aE);
                aE = fma((double)rE.w, (double)vE.w, aE);
                aO = fma((double)rO.x, (double)vO.x, aO);
                aO = fma((double)rO.y, (double)vO.y, aO);
                aO = fma((double)rO.z, (double)vO.z, aO);
                aO = fma((double)rO.w, (double)vO.w, aO);
            }
            double a = aE + aO;
            a += __shfl_xor(a, 1);
            const float dd = (float)(sq64[i] + sq64[col] - 2.0 * a);
            key = ((unsigned long long)fkey(dd) << 32) | (unsigned)col;
        } else {
            __shfl_xor(0.0, 1);   // keep pair shuffle uniform (no-op value)
        }
    }
    if (t < RCAND) kbuf[t] = ~0ull;
    __syncthreads();
    if (h == 0 && (unsigned)c < emitted) kbuf[c] = key;
    __syncthreads();

    // rank by (f32 dist, col); top-32 become the source list (+ self at 32)
    if (t < RCAND) {
        const unsigned long long key2 = kbuf[t];
        int rank = 0;
#pragma unroll 8
        for (int j = 0; j < RCAND; ++j)
            rank += (kbuf[j] < key2) ? 1 : 0;
        if (key2 != ~0ull && rank < KNB)
            srcS[rank] = (int)(key2 & 0xFFFFu);
    }
    if (t == 0) srcS[KNB] = i;
    __syncthreads();

    // ---- GAT attention epilogue (reads srcS) ----
    {   // stage 33 hl16 rows: 32 threads x 16B per row
        const int sub = t & 31, rb = t >> 5;
#pragma unroll
        for (int s = 0; s < 5; ++s) {
            const int rk = s * 8 + rb;
            if (rk < NSRC)
                *(uint4*)&hbuf[rk][sub * 8] =
                    *(const uint4*)(hl16 + (size_t)srcS[rk] * DO + sub * 8);
        }
    }
    __syncthreads();

    const int wid = t >> 6;
    {
        const float4 hr4 = *(const float4*)(hr + (size_t)i * DO + lane * 4);
        const float4 at4 = *(const float4*)(att + lane * 4);
#pragma unroll 1
        for (int k = wid; k < NSRC; k += 4) {
            const __half2 h01 = *(const __half2*)&hbuf[k][lane * 4];
            const __half2 h23 = *(const __half2*)&hbuf[k][lane * 4 + 2];
            const float2 f01 = __half22float2(h01);
            const float2 f23 = __half22float2(h23);
            float z, p = 0.f;
            z = f01.x + hr4.x; p = fmaf(z > 0.f ? z : NEG * z, at4.x, p);
            z = f01.y + hr4.y; p = fmaf(z > 0.f ? z : NEG * z, at4.y, p);
            z = f23.x + hr4.z; p = fmaf(z > 0.f ? z : NEG * z, at4.z, p);
            z = f23.y + hr4.w; p = fmaf(z > 0.f ? z : NEG * z, at4.w, p);
#pragma unroll
            for (int off = 32; off >= 1; off >>= 1) p += __shfl_xor(p, off);
            if (lane == 0) eS[k] = p;
        }
    }
    __syncthreads();
    if (wid == 0) {
        const float v = (lane < NSRC) ? eS[lane] : -3.4e38f;
        float m = v;
#pragma unroll
        for (int off = 32; off >= 1; off >>= 1) m = fmaxf(m, __shfl_xor(m, off));
        float w = (lane < NSRC) ? __expf(v - m) : 0.f;
        float s = w;
#pragma unroll
        for (int off = 32; off >= 1; off >>= 1) s += __shfl_xor(s, off);
        if (lane < NSRC) alphaS[lane] = w / s;
    }
    __syncthreads();
    float o = bias[t];
#pragma unroll
    for (int k = 0; k < NSRC; ++k)
        o = fmaf(alphaS[k], __half2float(hbuf[k][t]), o);
    out[(size_t)i * DO + t] = o;
}

extern "C" void kernel_launch(void* const* d_in, const int* in_sizes, int n_in,
                              void* d_out, int out_size, void* d_ws, size_t ws_size,
                              hipStream_t stream) {
    const float* x    = (const float*)d_in[0];
    const float* Wl   = (const float*)d_in[1];
    const float* bl   = (const float*)d_in[2];
    const float* Wr   = (const float*)d_in[3];
    const float* br   = (const float*)d_in[4];
    const float* att  = (const float*)d_in[5];
    const float* bias = (const float*)d_in[6];
    float* out = (float*)d_out;

    char* ws = (char*)d_ws;
    unsigned short* Bh  = (unsigned short*)(ws + 0);          //  2,621,440
    double* sq64 = (double*)(ws + 2621440);                   //     80,128
    float*  sq32 = (float*)(ws + 2701568);                    //     40,960
    unsigned* Trow = (unsigned*)(ws + 2742528);               //     40,064
    unsigned* cnt  = (unsigned*)(ws + 2782592);               //     40,064
    unsigned* cand = (unsigned*)(ws + 2822656);               // 41,025,536
    __half* hl16 = (__half*)(ws + 43848192);                  //  5,120,000
    float*  hr   = (float*)(ws + 48968192);                   // 10,240,000
    // total = 59,208,192 bytes

    prep_k<<<dim3(NTILE), 256, 0, stream>>>(x, Bh, sq64, sq32, cnt,
                                            Wl, bl, Wr, br, hl16, hr);
    thresh_k<<<dim3(ATILE), 256, 0, stream>>>(Bh, sq32, Trow);
    knn_emit_k<<<dim3(ATILE / 2, NCB), 256, 0, stream>>>(Bh, sq32, Trow, cnt, cand);
    rerank_gat_k<<<dim3(NN), 256, 0, stream>>>(x, sq64, cand, cnt,
                                               hl16, hr, att, bias, out);
}

// Round 22
// 214.208 us; speedup vs baseline: 1.2158x; 1.0231x over previous
//
#include <hip/hip_runtime.h>
#include <hip/hip_fp16.h>

#define NN     10000
#define DI     128
#define DO     256
#define KNB    32
#define NSRC   33      // 32 neighbors + self
#define RB     16
#define NP2    10240
#define NTILE  640     // NP2/16 tiles (B side; A reuses these fragments)
#define ATILE  626     // row tiles (covers 10016 rows, pad zeroed)
#define NROWS  10016
#define NCB    20      // col blocks of 512
#define SEG    64      // per-(row,colblock) LDS staging capacity
#define CAP    1024    // per-row compact capacity (count ~312 +- 77 -> 9 sigma)
#define RSEL   64      // select rank: 32 + 32 ranks of slack for bf16-approx
                       // reordering (rank-32 FAILED in round 21: key16 is a
                       // truncation of the APPROX distance, not the exact one)
#define RCAND  128     // re-rank candidate capacity (64th key16 + ties)
#define NEG    0.2f

typedef __attribute__((ext_vector_type(8))) short bf16x8;
typedef __attribute__((ext_vector_type(4))) float f32x4;

// monotone map f32 -> u32 preserving < order (handles negatives)
__device__ __forceinline__ unsigned fkey(float f) {
    unsigned u = __float_as_uint(f);
    return (u & 0x80000000u) ? ~u : (u | 0x80000000u);
}
__device__ __forceinline__ unsigned short bf16rne(float f) {
    unsigned u = __float_as_uint(f);
    unsigned r = u + 0x7FFFu + ((u >> 16) & 1u);
    return (unsigned short)(r >> 16);
}

// Fused prep: stage 16 rows of x, emit bf16(hi) MFMA fragments (shared A/B
// lane layout), f64/f32 norms, zero cnt, AND compute hl16/hr.
__global__ __launch_bounds__(256) void prep_k(const float* __restrict__ x,
    unsigned short* __restrict__ Bh, double* __restrict__ sq64,
    float* __restrict__ sq32, unsigned* __restrict__ cnt,
    const float* __restrict__ Wl, const float* __restrict__ bl,
    const float* __restrict__ Wr, const float* __restrict__ br,
    __half* __restrict__ hl16, float* __restrict__ hr)
{
    __shared__ float xs[16][132];   // +4 pad: conflict-free strided reads
    const int t = threadIdx.x;
    const int tile = blockIdx.x;
    const int i0 = tile * 16;
    if (tile < 40) {
        const int idx = tile * 256 + t;
        if (idx < NROWS) cnt[idx] = 0;
    }
#pragma unroll
    for (int q = 0; q < 2; ++q) {
        const int idx = t + 256 * q;
        const int r = idx >> 5, c4 = idx & 31;
        float4 v = make_float4(0.f, 0.f, 0.f, 0.f);
        if (i0 + r < NN) v = *(const float4*)(x + (size_t)(i0 + r) * DI + c4 * 4);
        *(float4*)&xs[r][c4 * 4] = v;
    }
    __syncthreads();
    {
        const int ks = t >> 6, flane = t & 63;
        const int srow = flane & 15;
        const int kb = ks * 32 + ((flane >> 4) & 3) * 8;
        unsigned hi2[4];
#pragma unroll
        for (int j = 0; j < 4; ++j) {
            const float v0 = xs[srow][kb + 2 * j], v1 = xs[srow][kb + 2 * j + 1];
            hi2[j] = (unsigned)bf16rne(v0) | ((unsigned)bf16rne(v1) << 16);
        }
        *(uint4*)(Bh + ((size_t)(tile * 4 + ks) * 64 + flane) * 8) =
            make_uint4(hi2[0], hi2[1], hi2[2], hi2[3]);
    }
    {
        const int row = t >> 4, sub = t & 15;
        double s = 0.0;
#pragma unroll
        for (int q = 0; q < 8; ++q) {
            const float v = xs[row][sub * 8 + q];
            s = fma((double)v, (double)v, s);
        }
#pragma unroll
        for (int off = 8; off >= 1; off >>= 1) s += __shfl_xor(s, off);
        if (sub == 0) {
            const int gi = i0 + row;
            sq32[gi] = (gi < NN) ? (float)s : 0.f;
            if (gi < NROWS) sq64[gi] = s;
        }
    }
    // fused hgemm: h_l = x@W_l + b_l (fp16), h_r = x@W_r + b_r (f32)
    if (tile < NN / RB) {
        const int c = t;
        float accl[RB], accr[RB];
        const float blv = bl[c], brv = br[c];
#pragma unroll
        for (int r = 0; r < RB; ++r) { accl[r] = blv; accr[r] = brv; }
        for (int d = 0; d < DI; ++d) {
            const float wl = Wl[d * DO + c];
            const float wr = Wr[d * DO + c];
#pragma unroll
            for (int r = 0; r < RB; ++r) {
                const float xv = x[(size_t)(i0 + r) * DI + d];  // wave-uniform
                accl[r] = fmaf(xv, wl, accl[r]);
                accr[r] = fmaf(xv, wr, accr[r]);
            }
        }
#pragma unroll
        for (int r = 0; r < RB; ++r) {
            hl16[(size_t)(i0 + r) * DO + c] = __float2half(accl[r]);
            hr[(size_t)(i0 + r) * DO + c] = accr[r];
        }
    }
}

// Per-row threshold from the chunk-0 sample: 16th-smallest u16 key of the
// row's 512 distances -> Trow raw-u32 bound (bitwise-consistent with emit).
__global__ __launch_bounds__(256) void thresh_k(
    const unsigned short* __restrict__ Bh, const float* __restrict__ sq32,
    unsigned* __restrict__ Trow)
{
    __shared__ unsigned short dist16[RB][512];
    const int rt = blockIdx.x;
    const int r0 = rt * 16;
    const int t = threadIdx.x;
    const int wid = t >> 6, lane = t & 63;
    const int wbase = wid * 128, l15 = lane & 15, rgrp = (lane >> 4) * 4;

    bf16x8 ah[4];
#pragma unroll
    for (int ks = 0; ks < 4; ++ks)
        ah[ks] = *(const bf16x8*)(Bh + ((size_t)(rt * 4 + ks) * 64 + lane) * 8);
    float sqiv[4];
#pragma unroll
    for (int rg = 0; rg < 4; ++rg) sqiv[rg] = sq32[r0 + rgrp + rg];

#pragma unroll 1
    for (int ct = 0; ct < 8; ++ct) {
        const int ctg = wid * 8 + ct;
        bf16x8 bh[4];
#pragma unroll
        for (int ks = 0; ks < 4; ++ks)
            bh[ks] = *(const bf16x8*)(Bh + ((size_t)(ctg * 4 + ks) * 64 + lane) * 8);
        f32x4 acc = {0.f, 0.f, 0.f, 0.f};
#pragma unroll
        for (int ks = 0; ks < 4; ++ks)
            acc = __builtin_amdgcn_mfma_f32_16x16x32_bf16(ah[ks], bh[ks], acc, 0, 0, 0);
        const int col = wbase + ct * 16 + l15;
        const float sqj = sq32[col];
#pragma unroll
        for (int rg = 0; rg < 4; ++rg) {
            const int row = r0 + rgrp + rg;
            const float dd = __builtin_fmaf(-2.f, acc[rg], sqiv[rg] + sqj);
            unsigned k16 = (__float_as_uint(dd) >> 16) | 0x8000u;
            if (col >= NN || col == row) k16 = 0xFFFFu;
            dist16[rgrp + rg][col] = (unsigned short)k16;
        }
    }
    __syncthreads();

#pragma unroll 1
    for (int rr = 0; rr < 4; ++rr) {
        const int r = wid * 4 + rr;
        unsigned kk[8];
#pragma unroll
        for (int u = 0; u < 8; ++u) kk[u] = dist16[r][lane + 64 * u];
        unsigned lo = 0, hi = 0xFFFFu;
#pragma unroll 1
        for (int it = 0; it < 16; ++it) {
            const unsigned mid = (lo + hi) >> 1;
            int c2 = 0;
#pragma unroll
            for (int u = 0; u < 8; ++u)
                c2 += (int)__popcll(__ballot(kk[u] <= mid));
            if (c2 >= 16) hi = mid; else lo = mid;
        }
        if (lane == 0) Trow[r0 + r] = ((hi & 0x7FFFu) << 16) | 0xFFFFu;
    }
}

// Main pass (round-15 body — best measured: 60 VGPR, ~46% occ, 83 us):
// 32 rows x 512 cols per block, hi-only MFMA, threshold compare, per-lane
// LDS-atomic append, compact copy with one global atomic per row per block.
__global__ __launch_bounds__(256) void knn_emit_k(
    const unsigned short* __restrict__ Bh, const float* __restrict__ sq32,
    const unsigned* __restrict__ Trow, unsigned* __restrict__ cnt,
    unsigned* __restrict__ cand)
{
    __shared__ unsigned lcnt[32];
    __shared__ unsigned basebuf[32];
    __shared__ unsigned cbuf[32][SEG];   // 8 KB
    const int r0 = blockIdx.x * 32;
    const int cbase = blockIdx.y * 512;
    const int t = threadIdx.x;
    const int wid = t >> 6, lane = t & 63;
    const int wbase = wid * 128, l15 = lane & 15, rgrp = (lane >> 4) * 4;
    if (t < 32) lcnt[t] = 0;

    bf16x8 ah[2][4];
#pragma unroll
    for (int rt2 = 0; rt2 < 2; ++rt2)
#pragma unroll
        for (int ks = 0; ks < 4; ++ks) {
            const int rt = (r0 >> 4) + rt2;
            ah[rt2][ks] = *(const bf16x8*)(Bh + ((size_t)(rt * 4 + ks) * 64 + lane) * 8);
        }
    float sqiv[2][4];
    unsigned TUv[2][4];
#pragma unroll
    for (int rt2 = 0; rt2 < 2; ++rt2)
#pragma unroll
        for (int rg = 0; rg < 4; ++rg) {
            const int row = r0 + rt2 * 16 + rgrp + rg;
            sqiv[rt2][rg] = sq32[row];
            TUv[rt2][rg] = Trow[row];
        }
    float sqjv[8];
#pragma unroll
    for (int ct = 0; ct < 8; ++ct)
        sqjv[ct] = sq32[cbase + wbase + ct * 16 + l15];
    __syncthreads();

    const int ctg0 = (cbase >> 4) + wid * 8;

#pragma unroll 1
    for (int ct = 0; ct < 8; ++ct) {
        bf16x8 bh[4];
#pragma unroll
        for (int ks = 0; ks < 4; ++ks)
            bh[ks] = *(const bf16x8*)(Bh + ((size_t)((ctg0 + ct) * 4 + ks) * 64 + lane) * 8);
        f32x4 a0 = {0.f, 0.f, 0.f, 0.f}, a1 = {0.f, 0.f, 0.f, 0.f};
#pragma unroll
        for (int ks = 0; ks < 4; ++ks) {
            a0 = __builtin_amdgcn_mfma_f32_16x16x32_bf16(ah[0][ks], bh[ks], a0, 0, 0, 0);
            a1 = __builtin_amdgcn_mfma_f32_16x16x32_bf16(ah[1][ks], bh[ks], a1, 0, 0, 0);
        }
        const int col = cbase + wbase + ct * 16 + l15;
        const float sqj = sqjv[ct];
#pragma unroll
        for (int rt2 = 0; rt2 < 2; ++rt2)
#pragma unroll
            for (int rg = 0; rg < 4; ++rg) {
                const int lrow = rt2 * 16 + rgrp + rg;
                const float dd = __builtin_fmaf(-2.f, (rt2 ? a1 : a0)[rg],
                                                sqiv[rt2][rg] + sqj);
                const unsigned raw = __float_as_uint(dd);
                if ((raw <= TUv[rt2][rg]) && (col < NN) && (col != r0 + lrow)) {
                    const unsigned slot = atomicAdd(&lcnt[lrow], 1u);
                    if (slot < SEG)
                        cbuf[lrow][slot] =
                            (((raw >> 16) | 0x8000u) << 16) | (unsigned)col;
                }
            }
    }

    __syncthreads();
    if (t < 32) {
        unsigned c = lcnt[t]; if (c > SEG) c = SEG;
        lcnt[t] = c;
        basebuf[t] = atomicAdd(&cnt[r0 + t], c);   // one atomic per row per block
    }
    __syncthreads();
#pragma unroll
    for (int q = 0; q < (32 * SEG) / 256; ++q) {
        const int idx = t + 256 * q;
        const int lr = idx >> 6, sl = idx & 63;
        if ((unsigned)sl < lcnt[lr]) {
            const unsigned b = basebuf[lr] + (unsigned)sl;
            if (b < CAP) cand[(size_t)(r0 + lr) * CAP + b] = cbuf[lr][sl];
        }
    }
}

// Fused per-row tail: histogram locates the 64th-smallest key16 (32 ranks of
// slack over KNB for bf16-approx reordering); emit key16 <= T16 (~66); f64
// re-rank of emitted only; rank over emitted prefix; GAT attention epilogue.
__global__ __launch_bounds__(256) void rerank_gat_k(
    const float* __restrict__ x, const double* __restrict__ sq64,
    const unsigned* __restrict__ cand, const unsigned* __restrict__ cnt,
    const __half* __restrict__ hl16, const float* __restrict__ hr,
    const float* __restrict__ att, const float* __restrict__ bias,
    float* __restrict__ out)
{
    __shared__ unsigned hist[256];
    __shared__ unsigned hist2[256];
    __shared__ float xrs[DI];
    __shared__ unsigned cbuf[RCAND];
    __shared__ unsigned long long kbuf[RCAND];
    __shared__ unsigned sel[4];   // [0]=H, [1]=r, [2]=T16, [3]=emit count
    __shared__ int srcS[NSRC];
    __shared__ __align__(16) __half hbuf[NSRC][DO];   // 16,896 B
    __shared__ float eS[NSRC];
    __shared__ float alphaS[NSRC];
    const int i = blockIdx.x, t = threadIdx.x;
    const int lane = t & 63;

    hist[t] = 0; hist2[t] = 0;
    if (t >= 128 && t < 160)
        *(float4*)&xrs[(t - 128) * 4] =
            *(const float4*)(x + (size_t)i * DI + (t - 128) * 4);
    if (t == 0) { sel[0] = 0xFFFFFFFFu; sel[2] = 0xFFFFu; sel[3] = 0; }
    unsigned n = cnt[i]; if (n > CAP) n = CAP;
    unsigned kk[4];
#pragma unroll
    for (int u = 0; u < 4; ++u) {
        const unsigned idx = (unsigned)t + 256u * u;
        kk[u] = (idx < n) ? cand[(size_t)i * CAP + idx] : 0xFFFFFFFFu;
    }
    __syncthreads();

    // level 1: histogram of key16 high byte
#pragma unroll
    for (int u = 0; u < 4; ++u)
        if (kk[u] != 0xFFFFFFFFu) atomicAdd(&hist[kk[u] >> 24], 1u);
    __syncthreads();
    if (t < 64) {   // wave 0: scan 256 buckets, locate bucket holding rank RSEL
        unsigned h[4];
#pragma unroll
        for (int q = 0; q < 4; ++q) h[q] = hist[lane * 4 + q];
        const unsigned s = h[0] + h[1] + h[2] + h[3];
        unsigned pre = s;
#pragma unroll
        for (int off = 1; off < 64; off <<= 1) {
            const unsigned o = __shfl_up(pre, off);
            if (lane >= off) pre += o;
        }
        const unsigned B = pre - s;
        if (B < RSEL && B + s >= RSEL) {
            unsigned c = B, H = 0, rr = 0;
#pragma unroll
            for (int q = 0; q < 4; ++q) {
                if (c < RSEL && c + h[q] >= RSEL) { H = lane * 4 + q; rr = RSEL - c; break; }
                c += h[q];
            }
            sel[0] = H; sel[1] = rr;
        }
    }
    __syncthreads();
    const unsigned H = sel[0];

    // level 2: histogram of low byte within bucket H
    if (H != 0xFFFFFFFFu) {
#pragma unroll
        for (int u = 0; u < 4; ++u)
            if (kk[u] != 0xFFFFFFFFu && (kk[u] >> 24) == H)
                atomicAdd(&hist2[(kk[u] >> 16) & 0xFFu], 1u);
    }
    __syncthreads();
    if (t < 64 && H != 0xFFFFFFFFu) {
        const unsigned r = sel[1];
        unsigned h[4];
#pragma unroll
        for (int q = 0; q < 4; ++q) h[q] = hist2[lane * 4 + q];
        const unsigned s = h[0] + h[1] + h[2] + h[3];
        unsigned pre = s;
#pragma unroll
        for (int off = 1; off < 64; off <<= 1) {
            const unsigned o = __shfl_up(pre, off);
            if (lane >= off) pre += o;
        }
        const unsigned B = pre - s;
        if (B < r && B + s >= r) {
            unsigned c = B, L = 0;
#pragma unroll
            for (int q = 0; q < 4; ++q) {
                if (c < r && c + h[q] >= r) { L = lane * 4 + q; break; }
                c += h[q];
            }
            sel[2] = (H << 8) | L;
        }
    }
    __syncthreads();
    const unsigned T16 = sel[2];

    // emit all candidates with key16 <= T16 (>=64, typically ~66; cap RCAND)
    {
        const unsigned long long lml = (1ull << lane) - 1;
#pragma unroll
        for (int u = 0; u < 4; ++u) {
            const bool pass = (kk[u] != 0xFFFFFFFFu) && ((kk[u] >> 16) <= T16);
            const unsigned long long b = __ballot(pass);
            unsigned base = 0;
            if (lane == 0 && b) base = atomicAdd(&sel[3], (unsigned)__popcll(b));
            base = __shfl(base, 0);
            if (pass) {
                const int slot = (int)(base + (unsigned)__popcll(b & lml));
                if (slot < RCAND) cbuf[slot] = kk[u];
            }
        }
    }
    __syncthreads();

    // f64 dot: 2 lanes per candidate, only emitted slots; 2 accumulators.
    const unsigned emitted = sel[3] < RCAND ? sel[3] : RCAND;
    const int c = t >> 1, h = t & 1;
    unsigned long long key = ~0ull;
    if ((unsigned)c < emitted) {
        const int col = (int)(cbuf[c] & 0xFFFFu);   // emit guarantees col < NN
        const float* xc = x + (size_t)col * DI;
        double aE = 0.0, aO = 0.0;
#pragma unroll
        for (int q = 0; q < 8; ++q) {
            const int fiE = (2 * q) * 8 + h * 4;
            const int fiO = (2 * q + 1) * 8 + h * 4;
            const float4 vE = *(const float4*)(xc + fiE);
            const float4 rE = *(const float4*)(&xrs[fiE]);
            const float4 vO = *(const float4*)(xc + fiO);
            const float4 rO = *(const float4*)(&xrs[fiO]);
            aE = fma((double)rE.x, (double)vE.x, aE);
            aE = fma((double)rE.y, (double)vE.y, aE);
            aE = fma((double)rE.z, (double)vE.z, aE);
            aE = fma((double)rE.w, (double)vE.w, aE);
            aO = fma((double)rO.x, (double)vO.x, aO);
            aO = fma((double)rO.y, (double)vO.y, aO);
            aO = fma((double)rO.z, (double)vO.z, aO);
            aO = fma((double)rO.w, (double)vO.w, aO);
        }
        double a = aE + aO;
        a += __shfl_xor(a, 1);
        const float dd = (float)(sq64[i] + sq64[col] - 2.0 * a);
        key = ((unsigned long long)fkey(dd) << 32) | (unsigned)col;
    }
    if (h == 0 && c < RCAND) kbuf[c] = key;   // non-emitted slots get ~0ull
    __syncthreads();

    // rank by (f32 dist, col) over the emitted prefix; scatter top-32
    if (t < RCAND) {
        const unsigned long long key2 = kbuf[t];
        int rank = 0;
        for (unsigned j = 0; j < emitted; ++j)
            rank += (kbuf[j] < key2) ? 1 : 0;
        if (key2 != ~0ull && rank < KNB)
            srcS[rank] = (int)(key2 & 0xFFFFu);
    }
    if (t == 0) srcS[KNB] = i;
    __syncthreads();

    // ---- GAT attention epilogue (reads srcS) ----
    {   // stage 33 hl16 rows: 32 threads x 16B per row
        const int sub = t & 31, rb = t >> 5;
#pragma unroll
        for (int s = 0; s < 5; ++s) {
            const int rk = s * 8 + rb;
            if (rk < NSRC)
                *(uint4*)&hbuf[rk][sub * 8] =
                    *(const uint4*)(hl16 + (size_t)srcS[rk] * DO + sub * 8);
        }
    }
    __syncthreads();

    const int wid = t >> 6;
    {
        const float4 hr4 = *(const float4*)(hr + (size_t)i * DO + lane * 4);
        const float4 at4 = *(const float4*)(att + lane * 4);
#pragma unroll 1
        for (int k = wid; k < NSRC; k += 4) {
            const __half2 h01 = *(const __half2*)&hbuf[k][lane * 4];
            const __half2 h23 = *(const __half2*)&hbuf[k][lane * 4 + 2];
            const float2 f01 = __half22float2(h01);
            const float2 f23 = __half22float2(h23);
            float z, p = 0.f;
            z = f01.x + hr4.x; p = fmaf(z > 0.f ? z : NEG * z, at4.x, p);
            z = f01.y + hr4.y; p = fmaf(z > 0.f ? z : NEG * z, at4.y, p);
            z = f23.x + hr4.z; p = fmaf(z > 0.f ? z : NEG * z, at4.z, p);
            z = f23.y + hr4.w; p = fmaf(z > 0.f ? z : NEG * z, at4.w, p);
#pragma unroll
            for (int off = 32; off >= 1; off >>= 1) p += __shfl_xor(p, off);
            if (lane == 0) eS[k] = p;
        }
    }
    __syncthreads();
    if (wid == 0) {
        const float v = (lane < NSRC) ? eS[lane] : -3.4e38f;
        float m = v;
#pragma unroll
        for (int off = 32; off >= 1; off >>= 1) m = fmaxf(m, __shfl_xor(m, off));
        float w = (lane < NSRC) ? __expf(v - m) : 0.f;
        float s = w;
#pragma unroll
        for (int off = 32; off >= 1; off >>= 1) s += __shfl_xor(s, off);
        if (lane < NSRC) alphaS[lane] = w / s;
    }
    __syncthreads();
    float o = bias[t];
#pragma unroll
    for (int k = 0; k < NSRC; ++k)
        o = fmaf(alphaS[k], __half2float(hbuf[k][t]), o);
    out[(size_t)i * DO + t] = o;
}

extern "C" void kernel_launch(void* const* d_in, const int* in_sizes, int n_in,
                              void* d_out, int out_size, void* d_ws, size_t ws_size,
                              hipStream_t stream) {
    const float* x    = (const float*)d_in[0];
    const float* Wl   = (const float*)d_in[1];
    const float* bl   = (const float*)d_in[2];
    const float* Wr   = (const float*)d_in[3];
    const float* br   = (const float*)d_in[4];
    const float* att  = (const float*)d_in[5];
    const float* bias = (const float*)d_in[6];
    float* out = (float*)d_out;

    char* ws = (char*)d_ws;
    unsigned short* Bh  = (unsigned short*)(ws + 0);          //  2,621,440
    double* sq64 = (double*)(ws + 2621440);                   //     80,128
    float*  sq32 = (float*)(ws + 2701568);                    //     40,960
    unsigned* Trow = (unsigned*)(ws + 2742528);               //     40,064
    unsigned* cnt  = (unsigned*)(ws + 2782592);               //     40,064
    unsigned* cand = (unsigned*)(ws + 2822656);               // 41,025,536
    __half* hl16 = (__half*)(ws + 43848192);                  //  5,120,000
    float*  hr   = (float*)(ws + 48968192);                   // 10,240,000
    // total = 59,208,192 bytes

    prep_k<<<dim3(NTILE), 256, 0, stream>>>(x, Bh, sq64, sq32, cnt,
                                            Wl, bl, Wr, br, hl16, hr);
    thresh_k<<<dim3(ATILE), 256, 0, stream>>>(Bh, sq32, Trow);
    knn_emit_k<<<dim3(ATILE / 2, NCB), 256, 0, stream>>>(Bh, sq32, Trow, cnt, cand);
    rerank_gat_k<<<dim3(NN), 256, 0, stream>>>(x, sq64, cand, cnt,
                                               hl16, hr, att, bias, out);
}

// Round 23
// 212.986 us; speedup vs baseline: 1.2228x; 1.0057x over previous
//
#include <hip/hip_runtime.h>
#include <hip/hip_fp16.h>

#define NN     10000
#define DI     128
#define DO     256
#define KNB    32
#define NSRC   33      // 32 neighbors + self
#define RB     16
#define NP2    10240
#define NTILE  640     // NP2/16 tiles (B side; A reuses these fragments)
#define ATILE  626     // row tiles (covers 10016 rows, pad zeroed)
#define NROWS  10016
#define NCB    20      // col blocks of 512
#define SEG    64      // per-(row,colblock) LDS staging capacity
#define CAP    1024    // per-row compact capacity (count ~312 +- 77 -> 9 sigma)
#define RSEL   64      // select rank: 32 + 32 ranks of slack for bf16-approx
                       // reordering (rank-32 FAILED in round 21)
#define RCAND  128     // re-rank candidate capacity (64th key16 + ties)
#define NEG    0.2f

typedef __attribute__((ext_vector_type(8))) short bf16x8;
typedef __attribute__((ext_vector_type(4))) float f32x4;

// monotone map f32 -> u32 preserving < order (handles negatives)
__device__ __forceinline__ unsigned fkey(float f) {
    unsigned u = __float_as_uint(f);
    return (u & 0x80000000u) ? ~u : (u | 0x80000000u);
}
__device__ __forceinline__ unsigned short bf16rne(float f) {
    unsigned u = __float_as_uint(f);
    unsigned r = u + 0x7FFFu + ((u >> 16) & 1u);
    return (unsigned short)(r >> 16);
}

// Fused prep: stage 16 rows of x, emit bf16(hi) MFMA fragments (shared A/B
// lane layout), f64/f32 norms, zero cnt, AND compute hl16/hr.
__global__ __launch_bounds__(256) void prep_k(const float* __restrict__ x,
    unsigned short* __restrict__ Bh, double* __restrict__ sq64,
    float* __restrict__ sq32, unsigned* __restrict__ cnt,
    const float* __restrict__ Wl, const float* __restrict__ bl,
    const float* __restrict__ Wr, const float* __restrict__ br,
    __half* __restrict__ hl16, float* __restrict__ hr)
{
    __shared__ float xs[16][132];   // +4 pad: conflict-free strided reads
    const int t = threadIdx.x;
    const int tile = blockIdx.x;
    const int i0 = tile * 16;
    if (tile < 40) {
        const int idx = tile * 256 + t;
        if (idx < NROWS) cnt[idx] = 0;
    }
#pragma unroll
    for (int q = 0; q < 2; ++q) {
        const int idx = t + 256 * q;
        const int r = idx >> 5, c4 = idx & 31;
        float4 v = make_float4(0.f, 0.f, 0.f, 0.f);
        if (i0 + r < NN) v = *(const float4*)(x + (size_t)(i0 + r) * DI + c4 * 4);
        *(float4*)&xs[r][c4 * 4] = v;
    }
    __syncthreads();
    {
        const int ks = t >> 6, flane = t & 63;
        const int srow = flane & 15;
        const int kb = ks * 32 + ((flane >> 4) & 3) * 8;
        unsigned hi2[4];
#pragma unroll
        for (int j = 0; j < 4; ++j) {
            const float v0 = xs[srow][kb + 2 * j], v1 = xs[srow][kb + 2 * j + 1];
            hi2[j] = (unsigned)bf16rne(v0) | ((unsigned)bf16rne(v1) << 16);
        }
        *(uint4*)(Bh + ((size_t)(tile * 4 + ks) * 64 + flane) * 8) =
            make_uint4(hi2[0], hi2[1], hi2[2], hi2[3]);
    }
    {
        const int row = t >> 4, sub = t & 15;
        double s = 0.0;
#pragma unroll
        for (int q = 0; q < 8; ++q) {
            const float v = xs[row][sub * 8 + q];
            s = fma((double)v, (double)v, s);
        }
#pragma unroll
        for (int off = 8; off >= 1; off >>= 1) s += __shfl_xor(s, off);
        if (sub == 0) {
            const int gi = i0 + row;
            sq32[gi] = (gi < NN) ? (float)s : 0.f;
            if (gi < NROWS) sq64[gi] = s;
        }
    }
    // fused hgemm: h_l = x@W_l + b_l (fp16), h_r = x@W_r + b_r (f32)
    if (tile < NN / RB) {
        const int c = t;
        float accl[RB], accr[RB];
        const float blv = bl[c], brv = br[c];
#pragma unroll
        for (int r = 0; r < RB; ++r) { accl[r] = blv; accr[r] = brv; }
        for (int d = 0; d < DI; ++d) {
            const float wl = Wl[d * DO + c];
            const float wr = Wr[d * DO + c];
#pragma unroll
            for (int r = 0; r < RB; ++r) {
                const float xv = x[(size_t)(i0 + r) * DI + d];  // wave-uniform
                accl[r] = fmaf(xv, wl, accl[r]);
                accr[r] = fmaf(xv, wr, accr[r]);
            }
        }
#pragma unroll
        for (int r = 0; r < RB; ++r) {
            hl16[(size_t)(i0 + r) * DO + c] = __float2half(accl[r]);
            hr[(size_t)(i0 + r) * DO + c] = accr[r];
        }
    }
}

// Per-row threshold from the chunk-0 sample: 16th-smallest u16 key of the
// row's 512 distances -> Trow raw-u32 bound (bitwise-consistent with emit).
__global__ __launch_bounds__(256) void thresh_k(
    const unsigned short* __restrict__ Bh, const float* __restrict__ sq32,
    unsigned* __restrict__ Trow)
{
    __shared__ unsigned short dist16[RB][512];
    const int rt = blockIdx.x;
    const int r0 = rt * 16;
    const int t = threadIdx.x;
    const int wid = t >> 6, lane = t & 63;
    const int wbase = wid * 128, l15 = lane & 15, rgrp = (lane >> 4) * 4;

    bf16x8 ah[4];
#pragma unroll
    for (int ks = 0; ks < 4; ++ks)
        ah[ks] = *(const bf16x8*)(Bh + ((size_t)(rt * 4 + ks) * 64 + lane) * 8);
    float sqiv[4];
#pragma unroll
    for (int rg = 0; rg < 4; ++rg) sqiv[rg] = sq32[r0 + rgrp + rg];

#pragma unroll 1
    for (int ct = 0; ct < 8; ++ct) {
        const int ctg = wid * 8 + ct;
        bf16x8 bh[4];
#pragma unroll
        for (int ks = 0; ks < 4; ++ks)
            bh[ks] = *(const bf16x8*)(Bh + ((size_t)(ctg * 4 + ks) * 64 + lane) * 8);
        f32x4 acc = {0.f, 0.f, 0.f, 0.f};
#pragma unroll
        for (int ks = 0; ks < 4; ++ks)
            acc = __builtin_amdgcn_mfma_f32_16x16x32_bf16(ah[ks], bh[ks], acc, 0, 0, 0);
        const int col = wbase + ct * 16 + l15;
        const float sqj = sq32[col];
#pragma unroll
        for (int rg = 0; rg < 4; ++rg) {
            const int row = r0 + rgrp + rg;
            const float dd = __builtin_fmaf(-2.f, acc[rg], sqiv[rg] + sqj);
            unsigned k16 = (__float_as_uint(dd) >> 16) | 0x8000u;
            if (col >= NN || col == row) k16 = 0xFFFFu;
            dist16[rgrp + rg][col] = (unsigned short)k16;
        }
    }
    __syncthreads();

#pragma unroll 1
    for (int rr = 0; rr < 4; ++rr) {
        const int r = wid * 4 + rr;
        unsigned kk[8];
#pragma unroll
        for (int u = 0; u < 8; ++u) kk[u] = dist16[r][lane + 64 * u];
        unsigned lo = 0, hi = 0xFFFFu;
#pragma unroll 1
        for (int it = 0; it < 16; ++it) {
            const unsigned mid = (lo + hi) >> 1;
            int c2 = 0;
#pragma unroll
            for (int u = 0; u < 8; ++u)
                c2 += (int)__popcll(__ballot(kk[u] <= mid));
            if (c2 >= 16) hi = mid; else lo = mid;
        }
        if (lane == 0) Trow[r0 + r] = ((hi & 0x7FFFu) << 16) | 0xFFFFu;
    }
}

// Main pass (round-15 body — best measured: 60 VGPR, ~46% occ, 83 us):
// 32 rows x 512 cols per block, hi-only MFMA, threshold compare, per-lane
// LDS-atomic append, compact copy with one global atomic per row per block.
__global__ __launch_bounds__(256) void knn_emit_k(
    const unsigned short* __restrict__ Bh, const float* __restrict__ sq32,
    const unsigned* __restrict__ Trow, unsigned* __restrict__ cnt,
    unsigned* __restrict__ cand)
{
    __shared__ unsigned lcnt[32];
    __shared__ unsigned basebuf[32];
    __shared__ unsigned cbuf[32][SEG];   // 8 KB
    const int r0 = blockIdx.x * 32;
    const int cbase = blockIdx.y * 512;
    const int t = threadIdx.x;
    const int wid = t >> 6, lane = t & 63;
    const int wbase = wid * 128, l15 = lane & 15, rgrp = (lane >> 4) * 4;
    if (t < 32) lcnt[t] = 0;

    bf16x8 ah[2][4];
#pragma unroll
    for (int rt2 = 0; rt2 < 2; ++rt2)
#pragma unroll
        for (int ks = 0; ks < 4; ++ks) {
            const int rt = (r0 >> 4) + rt2;
            ah[rt2][ks] = *(const bf16x8*)(Bh + ((size_t)(rt * 4 + ks) * 64 + lane) * 8);
        }
    float sqiv[2][4];
    unsigned TUv[2][4];
#pragma unroll
    for (int rt2 = 0; rt2 < 2; ++rt2)
#pragma unroll
        for (int rg = 0; rg < 4; ++rg) {
            const int row = r0 + rt2 * 16 + rgrp + rg;
            sqiv[rt2][rg] = sq32[row];
            TUv[rt2][rg] = Trow[row];
        }
    float sqjv[8];
#pragma unroll
    for (int ct = 0; ct < 8; ++ct)
        sqjv[ct] = sq32[cbase + wbase + ct * 16 + l15];
    __syncthreads();

    const int ctg0 = (cbase >> 4) + wid * 8;

#pragma unroll 1
    for (int ct = 0; ct < 8; ++ct) {
        bf16x8 bh[4];
#pragma unroll
        for (int ks = 0; ks < 4; ++ks)
            bh[ks] = *(const bf16x8*)(Bh + ((size_t)((ctg0 + ct) * 4 + ks) * 64 + lane) * 8);
        f32x4 a0 = {0.f, 0.f, 0.f, 0.f}, a1 = {0.f, 0.f, 0.f, 0.f};
#pragma unroll
        for (int ks = 0; ks < 4; ++ks) {
            a0 = __builtin_amdgcn_mfma_f32_16x16x32_bf16(ah[0][ks], bh[ks], a0, 0, 0, 0);
            a1 = __builtin_amdgcn_mfma_f32_16x16x32_bf16(ah[1][ks], bh[ks], a1, 0, 0, 0);
        }
        const int col = cbase + wbase + ct * 16 + l15;
        const float sqj = sqjv[ct];
#pragma unroll
        for (int rt2 = 0; rt2 < 2; ++rt2)
#pragma unroll
            for (int rg = 0; rg < 4; ++rg) {
                const int lrow = rt2 * 16 + rgrp + rg;
                const float dd = __builtin_fmaf(-2.f, (rt2 ? a1 : a0)[rg],
                                                sqiv[rt2][rg] + sqj);
                const unsigned raw = __float_as_uint(dd);
                if ((raw <= TUv[rt2][rg]) && (col < NN) && (col != r0 + lrow)) {
                    const unsigned slot = atomicAdd(&lcnt[lrow], 1u);
                    if (slot < SEG)
                        cbuf[lrow][slot] =
                            (((raw >> 16) | 0x8000u) << 16) | (unsigned)col;
                }
            }
    }

    __syncthreads();
    if (t < 32) {
        unsigned c = lcnt[t]; if (c > SEG) c = SEG;
        lcnt[t] = c;
        basebuf[t] = atomicAdd(&cnt[r0 + t], c);   // one atomic per row per block
    }
    __syncthreads();
#pragma unroll
    for (int q = 0; q < (32 * SEG) / 256; ++q) {
        const int idx = t + 256 * q;
        const int lr = idx >> 6, sl = idx & 63;
        if ((unsigned)sl < lcnt[lr]) {
            const unsigned b = basebuf[lr] + (unsigned)sl;
            if (b < CAP) cand[(size_t)(r0 + lr) * CAP + b] = cbuf[lr][sl];
        }
    }
}

// Fused per-row tail: histogram 64th-smallest key16 -> emit superset -> f64
// re-rank -> rank -> GAT attention. NO hbuf staging: hl16 is 5 MB and fully
// L2/L3-resident; both attention phases read it coalesced directly, cutting
// LDS 21.5 -> ~4.5 KB so occupancy reaches the 8-block thread cap.
__global__ __launch_bounds__(256) void rerank_gat_k(
    const float* __restrict__ x, const double* __restrict__ sq64,
    const unsigned* __restrict__ cand, const unsigned* __restrict__ cnt,
    const __half* __restrict__ hl16, const float* __restrict__ hr,
    const float* __restrict__ att, const float* __restrict__ bias,
    float* __restrict__ out)
{
    __shared__ unsigned hist[256];
    __shared__ unsigned hist2[256];
    __shared__ float xrs[DI];
    __shared__ unsigned cbuf[RCAND];
    __shared__ unsigned long long kbuf[RCAND];
    __shared__ unsigned sel[4];   // [0]=H, [1]=r, [2]=T16, [3]=emit count
    __shared__ int srcS[NSRC];
    __shared__ float eS[NSRC];
    __shared__ float alphaS[NSRC];
    const int i = blockIdx.x, t = threadIdx.x;
    const int lane = t & 63;

    hist[t] = 0; hist2[t] = 0;
    if (t >= 128 && t < 160)
        *(float4*)&xrs[(t - 128) * 4] =
            *(const float4*)(x + (size_t)i * DI + (t - 128) * 4);
    if (t == 0) { sel[0] = 0xFFFFFFFFu; sel[2] = 0xFFFFu; sel[3] = 0; }
    unsigned n = cnt[i]; if (n > CAP) n = CAP;
    unsigned kk[4];
#pragma unroll
    for (int u = 0; u < 4; ++u) {
        const unsigned idx = (unsigned)t + 256u * u;
        kk[u] = (idx < n) ? cand[(size_t)i * CAP + idx] : 0xFFFFFFFFu;
    }
    __syncthreads();

    // level 1: histogram of key16 high byte
#pragma unroll
    for (int u = 0; u < 4; ++u)
        if (kk[u] != 0xFFFFFFFFu) atomicAdd(&hist[kk[u] >> 24], 1u);
    __syncthreads();
    if (t < 64) {   // wave 0: scan 256 buckets, locate bucket holding rank RSEL
        unsigned h[4];
#pragma unroll
        for (int q = 0; q < 4; ++q) h[q] = hist[lane * 4 + q];
        const unsigned s = h[0] + h[1] + h[2] + h[3];
        unsigned pre = s;
#pragma unroll
        for (int off = 1; off < 64; off <<= 1) {
            const unsigned o = __shfl_up(pre, off);
            if (lane >= off) pre += o;
        }
        const unsigned B = pre - s;
        if (B < RSEL && B + s >= RSEL) {
            unsigned c = B, H = 0, rr = 0;
#pragma unroll
            for (int q = 0; q < 4; ++q) {
                if (c < RSEL && c + h[q] >= RSEL) { H = lane * 4 + q; rr = RSEL - c; break; }
                c += h[q];
            }
            sel[0] = H; sel[1] = rr;
        }
    }
    __syncthreads();
    const unsigned H = sel[0];

    // level 2: histogram of low byte within bucket H
    if (H != 0xFFFFFFFFu) {
#pragma unroll
        for (int u = 0; u < 4; ++u)
            if (kk[u] != 0xFFFFFFFFu && (kk[u] >> 24) == H)
                atomicAdd(&hist2[(kk[u] >> 16) & 0xFFu], 1u);
    }
    __syncthreads();
    if (t < 64 && H != 0xFFFFFFFFu) {
        const unsigned r = sel[1];
        unsigned h[4];
#pragma unroll
        for (int q = 0; q < 4; ++q) h[q] = hist2[lane * 4 + q];
        const unsigned s = h[0] + h[1] + h[2] + h[3];
        unsigned pre = s;
#pragma unroll
        for (int off = 1; off < 64; off <<= 1) {
            const unsigned o = __shfl_up(pre, off);
            if (lane >= off) pre += o;
        }
        const unsigned B = pre - s;
        if (B < r && B + s >= r) {
            unsigned c = B, L = 0;
#pragma unroll
            for (int q = 0; q < 4; ++q) {
                if (c < r && c + h[q] >= r) { L = lane * 4 + q; break; }
                c += h[q];
            }
            sel[2] = (H << 8) | L;
        }
    }
    __syncthreads();
    const unsigned T16 = sel[2];

    // emit all candidates with key16 <= T16 (>=64, typically ~66; cap RCAND)
    {
        const unsigned long long lml = (1ull << lane) - 1;
#pragma unroll
        for (int u = 0; u < 4; ++u) {
            const bool pass = (kk[u] != 0xFFFFFFFFu) && ((kk[u] >> 16) <= T16);
            const unsigned long long b = __ballot(pass);
            unsigned base = 0;
            if (lane == 0 && b) base = atomicAdd(&sel[3], (unsigned)__popcll(b));
            base = __shfl(base, 0);
            if (pass) {
                const int slot = (int)(base + (unsigned)__popcll(b & lml));
                if (slot < RCAND) cbuf[slot] = kk[u];
            }
        }
    }
    __syncthreads();

    // f64 dot: 2 lanes per candidate, only emitted slots; 2 accumulators.
    const unsigned emitted = sel[3] < RCAND ? sel[3] : RCAND;
    const int c = t >> 1, h = t & 1;
    unsigned long long key = ~0ull;
    if ((unsigned)c < emitted) {
        const int col = (int)(cbuf[c] & 0xFFFFu);   // emit guarantees col < NN
        const float* xc = x + (size_t)col * DI;
        double aE = 0.0, aO = 0.0;
#pragma unroll
        for (int q = 0; q < 8; ++q) {
            const int fiE = (2 * q) * 8 + h * 4;
            const int fiO = (2 * q + 1) * 8 + h * 4;
            const float4 vE = *(const float4*)(xc + fiE);
            const float4 rE = *(const float4*)(&xrs[fiE]);
            const float4 vO = *(const float4*)(xc + fiO);
            const float4 rO = *(const float4*)(&xrs[fiO]);
            aE = fma((double)rE.x, (double)vE.x, aE);
            aE = fma((double)rE.y, (double)vE.y, aE);
            aE = fma((double)rE.z, (double)vE.z, aE);
            aE = fma((double)rE.w, (double)vE.w, aE);
            aO = fma((double)rO.x, (double)vO.x, aO);
            aO = fma((double)rO.y, (double)vO.y, aO);
            aO = fma((double)rO.z, (double)vO.z, aO);
            aO = fma((double)rO.w, (double)vO.w, aO);
        }
        double a = aE + aO;
        a += __shfl_xor(a, 1);
        const float dd = (float)(sq64[i] + sq64[col] - 2.0 * a);
        key = ((unsigned long long)fkey(dd) << 32) | (unsigned)col;
    }
    if (h == 0 && c < RCAND) kbuf[c] = key;   // non-emitted slots get ~0ull
    __syncthreads();

    // rank by (f32 dist, col) over the emitted prefix; scatter top-32
    if (t < RCAND) {
        const unsigned long long key2 = kbuf[t];
        int rank = 0;
        for (unsigned j = 0; j < emitted; ++j)
            rank += (kbuf[j] < key2) ? 1 : 0;
        if (key2 != ~0ull && rank < KNB)
            srcS[rank] = (int)(key2 & 0xFFFFu);
    }
    if (t == 0) srcS[KNB] = i;
    __syncthreads();

    // ---- GAT attention epilogue: direct L2-resident hl16 reads ----
    const int wid = t >> 6;
    {
        const float4 hr4 = *(const float4*)(hr + (size_t)i * DO + lane * 4);
        const float4 at4 = *(const float4*)(att + lane * 4);
#pragma unroll 1
        for (int k = wid; k < NSRC; k += 4) {
            const __half2* hp =
                (const __half2*)(hl16 + (size_t)srcS[k] * DO + lane * 4);
            const float2 f01 = __half22float2(hp[0]);
            const float2 f23 = __half22float2(hp[1]);
            float z, p = 0.f;
            z = f01.x + hr4.x; p = fmaf(z > 0.f ? z : NEG * z, at4.x, p);
            z = f01.y + hr4.y; p = fmaf(z > 0.f ? z : NEG * z, at4.y, p);
            z = f23.x + hr4.z; p = fmaf(z > 0.f ? z : NEG * z, at4.z, p);
            z = f23.y + hr4.w; p = fmaf(z > 0.f ? z : NEG * z, at4.w, p);
#pragma unroll
            for (int off = 32; off >= 1; off >>= 1) p += __shfl_xor(p, off);
            if (lane == 0) eS[k] = p;
        }
    }
    __syncthreads();
    if (wid == 0) {
        const float v = (lane < NSRC) ? eS[lane] : -3.4e38f;
        float m = v;
#pragma unroll
        for (int off = 32; off >= 1; off >>= 1) m = fmaxf(m, __shfl_xor(m, off));
        float w = (lane < NSRC) ? __expf(v - m) : 0.f;
        float s = w;
#pragma unroll
        for (int off = 32; off >= 1; off >>= 1) s += __shfl_xor(s, off);
        if (lane < NSRC) alphaS[lane] = w / s;
    }
    __syncthreads();
    float o = bias[t];
#pragma unroll 8
    for (int k = 0; k < NSRC; ++k)
        o = fmaf(alphaS[k], __half2float(hl16[(size_t)srcS[k] * DO + t]), o);
    out[(size_t)i * DO + t] = o;
}

extern "C" void kernel_launch(void* const* d_in, const int* in_sizes, int n_in,
                              void* d_out, int out_size, void* d_ws, size_t ws_size,
                              hipStream_t stream) {
    const float* x    = (const float*)d_in[0];
    const float* Wl   = (const float*)d_in[1];
    const float* bl   = (const float*)d_in[2];
    const float* Wr   = (const float*)d_in[3];
    const float* br   = (const float*)d_in[4];
    const float* att  = (const float*)d_in[5];
    const float* bias = (const float*)d_in[6];
    float* out = (float*)d_out;

    char* ws = (char*)d_ws;
    unsigned short* Bh  = (unsigned short*)(ws + 0);          //  2,621,440
    double* sq64 = (double*)(ws + 2621440);                   //     80,128
    float*  sq32 = (float*)(ws + 2701568);                    //     40,960
    unsigned* Trow = (unsigned*)(ws + 2742528);               //     40,064
    unsigned* cnt  = (unsigned*)(ws + 2782592);               //     40,064
    unsigned* cand = (unsigned*)(ws + 2822656);               // 41,025,536
    __half* hl16 = (__half*)(ws + 43848192);                  //  5,120,000
    float*  hr   = (float*)(ws + 48968192);                   // 10,240,000
    // total = 59,208,192 bytes

    prep_k<<<dim3(NTILE), 256, 0, stream>>>(x, Bh, sq64, sq32, cnt,
                                            Wl, bl, Wr, br, hl16, hr);
    thresh_k<<<dim3(ATILE), 256, 0, stream>>>(Bh, sq32, Trow);
    knn_emit_k<<<dim3(ATILE / 2, NCB), 256, 0, stream>>>(Bh, sq32, Trow, cnt, cand);
    rerank_gat_k<<<dim3(NN), 256, 0, stream>>>(x, sq64, cand, cnt,
                                               hl16, hr, att, bias, out);
}